// Round 9
// baseline (425.814 us; speedup 1.0000x reference)
//
#include <hip/hip_runtime.h>
#include <cstdint>
#include <cstddef>

#define NB 4
#define CH 256
#define SS 4096
#define EE 128
#define QSCALE 0.08838834764831845f /* 1/sqrt(128) */

typedef __attribute__((ext_vector_type(8))) short bfrag;          // 8 bf16 = 4 VGPR
typedef __attribute__((ext_vector_type(8))) unsigned short u16x8; // 16B ld/st
typedef __attribute__((ext_vector_type(8))) _Float16 h16x8;       // 16B fp16
typedef __attribute__((ext_vector_type(4))) float f32x4;          // MFMA acc

__device__ __forceinline__ unsigned short f2bf(float f) {
  union { float f; unsigned int u; } v; v.f = f;
  unsigned int u = v.u;
  unsigned int r = u + 0x7FFFu + ((u >> 16) & 1u);  // RNE
  return (unsigned short)(r >> 16);
}
__device__ __forceinline__ float bf2f(unsigned short u) {
  union { unsigned int u; float f; } v; v.u = ((unsigned int)u) << 16;
  return v.f;
}

// LDS-only barrier: waits DS ops, leaves global loads in flight.
__device__ __forceinline__ void lds_barrier() {
  asm volatile("s_waitcnt lgkmcnt(0)" ::: "memory");
  __builtin_amdgcn_s_barrier();
}

// ---------------------------------------------------------------------------
// Pass 0: weights-only fp32 -> bf16
// ---------------------------------------------------------------------------
__global__ __launch_bounds__(256) void cvt_w(
    const float* __restrict__ thw, const float* __restrict__ phw,
    const float* __restrict__ pw,
    unsigned short* __restrict__ thwb, unsigned short* __restrict__ phwb,
    unsigned short* __restrict__ pwb)
{
  const int nw4 = EE * CH / 4;   // 8192
  const int np4 = CH * CH / 4;   // 16384
  int i = blockIdx.x * 256 + threadIdx.x;
  const float* src; unsigned short* dst; int off;
  if      (i < nw4)           { src = thw; dst = thwb; off = i; }
  else if (i < 2 * nw4)       { src = phw; dst = phwb; off = i - nw4; }
  else if (i < 2 * nw4 + np4) { src = pw;  dst = pwb;  off = i - 2 * nw4; }
  else return;
  float4 v = reinterpret_cast<const float4*>(src)[off];
  ushort4 o;
  o.x = f2bf(v.x); o.y = f2bf(v.y); o.z = f2bf(v.z); o.w = f2bf(v.w);
  reinterpret_cast<ushort4*>(dst)[off] = o;
}

// ---------------------------------------------------------------------------
// Pass 1 (fused): x fp32->bf16 (xb byproduct) + theta/phi projections.
// ---------------------------------------------------------------------------
__global__ __launch_bounds__(512) void pass1_qk(
    const float* __restrict__ x,
    const unsigned short* __restrict__ thw,
    const unsigned short* __restrict__ phw,
    unsigned short* __restrict__ xb,
    unsigned short* __restrict__ Qt,
    unsigned short* __restrict__ Kt)
{
  __shared__ unsigned short xT[64][CH + 8];
  const int t  = threadIdx.x;
  const int n  = blockIdx.y;
  const int s0 = blockIdx.x * 64;

  {
    const int soff = (t & 15) * 4;
    const int c0   = t >> 4;           // 0..31
    #pragma unroll
    for (int ci = 0; ci < 8; ++ci) {
      const int c = c0 + ci * 32;
      const size_t rowoff = ((size_t)n * CH + c) * SS + s0;
      float4 v = reinterpret_cast<const float4*>(x + rowoff)[soff >> 2];
      ushort4 o;
      o.x = f2bf(v.x); o.y = f2bf(v.y); o.z = f2bf(v.z); o.w = f2bf(v.w);
      reinterpret_cast<ushort4*>(xb + rowoff)[soff >> 2] = o;
      xT[soff + 0][c] = o.x;
      xT[soff + 1][c] = o.y;
      xT[soff + 2][c] = o.z;
      xT[soff + 3][c] = o.w;
    }
  }
  __syncthreads();

  const int w    = t >> 6;        // 0..7
  const int lane = t & 63;
  const int q    = lane >> 4;
  const int mr   = lane & 15;
  const int wrow = (w & 3) * 16;
  const int half = w >> 2;        // 0: theta->Qt, 1: phi->Kt

  bfrag a[8];
  {
    const bfrag* rp = reinterpret_cast<const bfrag*>(&xT[wrow + mr][0]);
    #pragma unroll
    for (int k = 0; k < 8; ++k) a[k] = rp[k * 4 + q];
  }

  const unsigned short* wsel = half ? phw : thw;
  unsigned short*       osel = half ? Kt  : Qt;
  const float           sc   = half ? 1.0f : QSCALE;
  const bfrag* wp = reinterpret_cast<const bfrag*>(wsel);
  #pragma unroll
  for (int nt = 0; nt < 8; ++nt) {
    f32x4 acc = {0.f, 0.f, 0.f, 0.f};
    #pragma unroll
    for (int k = 0; k < 8; ++k) {
      bfrag b = wp[(nt * 16 + mr) * (CH / 8) + k * 4 + q];
      acc = __builtin_amdgcn_mfma_f32_16x16x32_bf16(a[k], b, acc, 0, 0, 0);
    }
    #pragma unroll
    for (int i = 0; i < 4; ++i) {
      const int srow = s0 + wrow + q * 4 + i;
      osel[((size_t)n * SS + srow) * EE + nt * 16 + mr] = f2bf(acc[i] * sc);
    }
  }
}

// ---------------------------------------------------------------------------
// Pass 2a (r9): partial flash attention, Q-tile 128, keys QUARTERED (1024 per
// block, 512 blocks) so TWO independent blocks co-reside per CU (LDS 68 KB,
// VGPR capped 128 via launch_bounds(512,4)) -- cross-block overlap of the
// QK/softmax/PV phases that serialize within a block (the measured ~95us
// compute floor: MfmaUtil 21 + VALUBusy 29, 50% barrier stall).
// Footprint diet: S stored bf16 with P written IN-PLACE (each softmax thread
// owns cols cg*16..+15 of row r for read AND write -> race-free); K tile
// staged in LDS once (no r8-style duplication); K prefetch is split
// issue-early/write-late (T14); barriers are lgkmcnt-only.
// ---------------------------------------------------------------------------
__global__ __launch_bounds__(512, 4) void pass2a(
    const unsigned short* __restrict__ Qt,
    const unsigned short* __restrict__ Kt,
    const unsigned short* __restrict__ xb,
    _Float16* __restrict__ Opart,
    float* __restrict__ ML)
{
  //   [0      .. 33792)  Q_lds u16[128][132]
  //   [33792  .. 51200)  SP    u16[128][68]   (S bf16, P in place)
  //   [51200  .. 68096)  K_lds u16[64][132]
  //   [68096  .. 69632)  row_m / row_l / row_alpha  f32[128] each
  __shared__ __align__(16) unsigned char SMEM[69632];
  unsigned short (*Q_lds)[132] = reinterpret_cast<unsigned short(*)[132]>(SMEM);
  unsigned short (*SP)[68]     = reinterpret_cast<unsigned short(*)[68]>(SMEM + 33792);
  unsigned short (*K_lds)[132] = reinterpret_cast<unsigned short(*)[132]>(SMEM + 51200);
  float* row_m     = reinterpret_cast<float*>(SMEM + 68096);
  float* row_l     = reinterpret_cast<float*>(SMEM + 68608);
  float* row_alpha = reinterpret_cast<float*>(SMEM + 69120);

  const int t       = threadIdx.x;
  const int id      = blockIdx.x;
  const int xcd     = id & 7;
  const int n       = xcd >> 1;                       // image pinned to XCD pair
  const int quarter = (xcd & 1) * 2 + ((id >> 3) & 1);
  const int qt      = id >> 4;                        // 0..31
  const int s0      = qt * 128;
  const int kq0     = quarter * 1024;

  const int w    = t >> 6;        // 0..7
  const int lane = t & 63;
  const int q    = lane >> 4;
  const int mr   = lane & 15;
  const int rb   = (w >> 2) * 64; // QK row-half of this wave
  const int c4   = w & 3;         // QK key-col block (16 keys)

  if (t < 128) { row_m[t] = -INFINITY; row_l[t] = 0.f; }

  // stage Q tile 128x128 (coalesced 64B/thread)
  {
    const int r  = t >> 2;
    const int j0 = (t & 3) * 4;
    const unsigned short* src = Qt + ((size_t)n * SS + s0 + r) * EE;
    #pragma unroll
    for (int j = 0; j < 4; ++j) {
      const int col = (j0 + j) * 8;
      *reinterpret_cast<u16x8*>(&Q_lds[r][col]) =
          *reinterpret_cast<const u16x8*>(src + col);
    }
  }
  // stage K tile 0 (64 keys x 128e, 32B/thread)
  {
    const int key = t >> 3, c = t & 7;
    const unsigned short* src = Kt + ((size_t)n * SS + kq0 + key) * EE;
    *reinterpret_cast<u16x8*>(&K_lds[key][c * 8]) =
        *reinterpret_cast<const u16x8*>(src + c * 8);
    *reinterpret_cast<u16x8*>(&K_lds[key][(c + 8) * 8]) =
        *reinterpret_cast<const u16x8*>(src + (c + 8) * 8);
  }

  f32x4 o_accA[4][2], o_accB[4][2];
  #pragma unroll
  for (int ms = 0; ms < 4; ++ms)
    #pragma unroll
    for (int nt = 0; nt < 2; ++nt) {
      o_accA[ms][nt] = (f32x4){0.f, 0.f, 0.f, 0.f};
      o_accB[ms][nt] = (f32x4){0.f, 0.f, 0.f, 0.f};
    }

  __syncthreads();

#define PV_HALF(OACC, RB)                                                    \
  do {                                                                       \
    _Pragma("unroll")                                                        \
    for (int ms = 0; ms < 4; ++ms) {                                         \
      float al[4];                                                           \
      _Pragma("unroll")                                                      \
      for (int i = 0; i < 4; ++i) al[i] = row_alpha[(RB) + ms*16 + q*4 + i]; \
      _Pragma("unroll")                                                      \
      for (int nt = 0; nt < 2; ++nt)                                         \
        _Pragma("unroll")                                                    \
        for (int i = 0; i < 4; ++i) OACC[ms][nt][i] *= al[i];                \
    }                                                                        \
    _Pragma("unroll")                                                        \
    for (int kk = 0; kk < 2; ++kk) {                                         \
      bfrag pa[4];                                                           \
      _Pragma("unroll")                                                      \
      for (int ms = 0; ms < 4; ++ms)                                         \
        pa[ms] = *reinterpret_cast<const bfrag*>(                            \
            &SP[(RB) + ms * 16 + mr][(kk * 4 + q) * 8]);                     \
      _Pragma("unroll")                                                      \
      for (int nt = 0; nt < 2; ++nt)                                         \
        _Pragma("unroll")                                                    \
        for (int ms = 0; ms < 4; ++ms)                                       \
          OACC[ms][nt] = __builtin_amdgcn_mfma_f32_16x16x32_bf16(            \
              pa[ms], vb[kk][nt], OACC[ms][nt], 0, 0, 0);                    \
    }                                                                        \
  } while (0)

  for (int t0 = 0; t0 < 1024; t0 += 64) {
    // ---- V fragments for THIS iter (in flight across both barriers) ----
    bfrag vb[2][2];
    #pragma unroll
    for (int nt = 0; nt < 2; ++nt) {
      const int c = w * 32 + nt * 16 + mr;
      const bfrag* vp = reinterpret_cast<const bfrag*>(
          xb + ((size_t)n * CH + c) * SS + kq0 + t0);
      vb[0][nt] = vp[q];
      vb[1][nt] = vp[4 + q];
    }

    // ---- QK^T: wave -> rows rb..rb+63 x keys c4*16..+15, S written bf16 ----
    {
      bfrag kb[4];
      #pragma unroll
      for (int k = 0; k < 4; ++k)
        kb[k] = *reinterpret_cast<const bfrag*>(
            &K_lds[c4 * 16 + mr][(k * 4 + q) * 8]);
      #pragma unroll
      for (int ms = 0; ms < 4; ++ms) {
        f32x4 acc = {0.f, 0.f, 0.f, 0.f};
        #pragma unroll
        for (int k = 0; k < 4; ++k) {
          bfrag aq = *reinterpret_cast<const bfrag*>(
              &Q_lds[rb + ms * 16 + mr][(k * 4 + q) * 8]);
          acc = __builtin_amdgcn_mfma_f32_16x16x32_bf16(aq, kb[k], acc, 0, 0, 0);
        }
        #pragma unroll
        for (int i = 0; i < 4; ++i)
          SP[rb + ms * 16 + q * 4 + i][c4 * 16 + mr] = f2bf(acc[i]);
      }
    }
    lds_barrier();   // S visible

    // ---- K(i+1): issue global loads now, LDS-write after PV (T14 split) ----
    u16x8 kr0, kr1;
    const bool pf = (t0 + 64) < 1024;
    if (pf) {
      const int key = t >> 3, c = t & 7;
      const unsigned short* src =
          Kt + ((size_t)n * SS + kq0 + t0 + 64 + key) * EE;
      kr0 = *reinterpret_cast<const u16x8*>(src + c * 8);
      kr1 = *reinterpret_cast<const u16x8*>(src + (c + 8) * 8);
    }

    // ---- online softmax, P in place over S (4 lanes/row x 16 keys) ----
    {
      const int r  = t >> 2;
      const int cg = t & 3;
      u16x8 sv0 = *reinterpret_cast<const u16x8*>(&SP[r][cg * 16]);
      u16x8 sv1 = *reinterpret_cast<const u16x8*>(&SP[r][cg * 16 + 8]);
      float s[16];
      #pragma unroll
      for (int j = 0; j < 8; ++j) { s[j] = bf2f(sv0[j]); s[8 + j] = bf2f(sv1[j]); }
      float vmax = s[0];
      #pragma unroll
      for (int j = 1; j < 16; ++j) vmax = fmaxf(vmax, s[j]);
      vmax = fmaxf(vmax, __shfl_xor(vmax, 1, 4));
      vmax = fmaxf(vmax, __shfl_xor(vmax, 2, 4));
      const float m_old = row_m[r];
      const float m_new = fmaxf(m_old, vmax);
      float sum = 0.f;
      u16x8 pk0, pk1;
      #pragma unroll
      for (int j = 0; j < 8; ++j) {
        float p = __expf(s[j] - m_new); sum += p; pk0[j] = f2bf(p);
      }
      #pragma unroll
      for (int j = 0; j < 8; ++j) {
        float p = __expf(s[8 + j] - m_new); sum += p; pk1[j] = f2bf(p);
      }
      *reinterpret_cast<u16x8*>(&SP[r][cg * 16])     = pk0;
      *reinterpret_cast<u16x8*>(&SP[r][cg * 16 + 8]) = pk1;
      sum += __shfl_xor(sum, 1, 4);
      sum += __shfl_xor(sum, 2, 4);
      if (cg == 0) {
        const float al = __expf(m_old - m_new);   // exp(-inf)=0 on iter 0
        row_alpha[r] = al;
        row_m[r]     = m_new;
        row_l[r]     = row_l[r] * al + sum;
      }
    }
    lds_barrier();   // P + alpha visible

    // ---- rescale + PV (both row halves, this wave's 32 V cols) ----
    PV_HALF(o_accA, 0);
    PV_HALF(o_accB, 64);

    // ---- land K(i+1) into LDS (K_lds idle during PV) ----
    if (pf) {
      const int key = t >> 3, c = t & 7;
      *reinterpret_cast<u16x8*>(&K_lds[key][c * 8])       = kr0;
      *reinterpret_cast<u16x8*>(&K_lds[key][(c + 8) * 8]) = kr1;
    }
    lds_barrier();   // K(i+1) visible; P consumed before next QK
  }

  // ---- epilogue: normalized fp16 partials + (m,l) ----
  const size_t p = ((size_t)(n * 32 + qt)) * 4 + quarter;

#define EPI_HALF(OACC, RB)                                                   \
  do {                                                                       \
    _Pragma("unroll")                                                        \
    for (int ms = 0; ms < 4; ++ms) {                                         \
      float inv[4];                                                          \
      _Pragma("unroll")                                                      \
      for (int i = 0; i < 4; ++i)                                            \
        inv[i] = 1.0f / row_l[(RB) + ms * 16 + q * 4 + i];                   \
      _Pragma("unroll")                                                      \
      for (int nt = 0; nt < 2; ++nt)                                         \
        _Pragma("unroll")                                                    \
        for (int i = 0; i < 4; ++i) {                                        \
          const size_t oi =                                                  \
              (p * 128 + (RB) + ms * 16 + q * 4 + i) * 256 +                 \
              w * 32 + nt * 16 + mr;                                         \
          Opart[oi] = (_Float16)(OACC[ms][nt][i] * inv[i]);                  \
        }                                                                    \
    }                                                                        \
  } while (0)

  EPI_HALF(o_accA, 0);
  EPI_HALF(o_accB, 64);
  if (t < 128) {
    ML[p * 256 + t * 2]     = row_m[t];
    ML[p * 256 + t * 2 + 1] = row_l[t];
  }
}

// ---------------------------------------------------------------------------
// Pass 2b: 4-way merge of key-quarter partials + projection + residual.
// ---------------------------------------------------------------------------
__global__ __launch_bounds__(512) void pass2b(
    const _Float16* __restrict__ Opart,
    const float* __restrict__ ML,
    const unsigned short* __restrict__ pwb,
    const float* __restrict__ x,
    float* __restrict__ out)
{
  __shared__ __align__(16) unsigned char SMEM[34816];
  unsigned short (*Y_lds)[CH + 8] =
      reinterpret_cast<unsigned short(*)[CH + 8]>(SMEM);   // 64*264*2 = 33792
  float (*W)[64] = reinterpret_cast<float(*)[64]>(SMEM + 33792);  // 4x64 f32

  const int t   = threadIdx.x;
  const int id  = blockIdx.x;
  const int n   = id >> 6;
  const int sub = id & 63;
  const int s0  = sub * 64;
  const int qt  = sub >> 1;
  const int rb  = (sub & 1) * 64;          // row range within the q-tile
  const size_t p0 = ((size_t)(n * 32 + qt)) * 4;

  if (t < 64) {
    float m[4], l[4];
    #pragma unroll
    for (int qi = 0; qi < 4; ++qi) {
      m[qi] = ML[(p0 + qi) * 256 + (rb + t) * 2];
      l[qi] = ML[(p0 + qi) * 256 + (rb + t) * 2 + 1];
    }
    const float mm = fmaxf(fmaxf(m[0], m[1]), fmaxf(m[2], m[3]));
    float e[4], se = 0.f;
    #pragma unroll
    for (int qi = 0; qi < 4; ++qi) { e[qi] = __expf(m[qi] - mm) * l[qi]; se += e[qi]; }
    const float iL = 1.0f / se;
    #pragma unroll
    for (int qi = 0; qi < 4; ++qi) W[qi][t] = e[qi] * iL;
  }
  __syncthreads();

  // merge partials -> Y_lds (bf16)
  {
    const int r = t >> 3;
    #pragma unroll
    for (int seg = 0; seg < 4; ++seg) {
      const int c0 = (t & 7) * 8 + seg * 64;
      float acc[8] = {0.f, 0.f, 0.f, 0.f, 0.f, 0.f, 0.f, 0.f};
      #pragma unroll
      for (int qi = 0; qi < 4; ++qi) {
        h16x8 hv = *reinterpret_cast<const h16x8*>(
            Opart + ((p0 + qi) * 128 + rb + r) * 256 + c0);
        const float wq = W[qi][r];
        #pragma unroll
        for (int j = 0; j < 8; ++j) acc[j] += (float)hv[j] * wq;
      }
      u16x8 y;
      #pragma unroll
      for (int j = 0; j < 8; ++j) y[j] = f2bf(acc[j]);
      *reinterpret_cast<u16x8*>(&Y_lds[r][c0]) = y;
    }
  }
  __syncthreads();

  // projection + residual: wave w -> output rows o = w*32 .. w*32+31
  const int w    = t >> 6;
  const int lane = t & 63;
  const int q    = lane >> 4;
  const int mr   = lane & 15;
  #pragma unroll
  for (int ot = 0; ot < 2; ++ot) {
    const int o0 = w * 32 + ot * 16;
    bfrag a[8];
    {
      const bfrag* ap = reinterpret_cast<const bfrag*>(pwb + (o0 + mr) * CH);
      #pragma unroll
      for (int k = 0; k < 8; ++k) a[k] = ap[k * 4 + q];
    }
    #pragma unroll
    for (int st = 0; st < 4; ++st) {
      f32x4 acc = {0.f, 0.f, 0.f, 0.f};
      const bfrag* bp = reinterpret_cast<const bfrag*>(&Y_lds[st * 16 + mr][0]);
      #pragma unroll
      for (int k = 0; k < 8; ++k)
        acc = __builtin_amdgcn_mfma_f32_16x16x32_bf16(a[k], bp[k * 4 + q], acc, 0, 0, 0);
      #pragma unroll
      for (int i = 0; i < 4; ++i) {
        const int o = o0 + q * 4 + i;
        const int s = s0 + st * 16 + mr;
        const size_t idx = ((size_t)n * CH + o) * SS + s;
        out[idx] = x[idx] + acc[i];
      }
    }
  }
}

// ---------------------------------------------------------------------------
// Fallback (ws too small for partials): round-5 fused full-key kernel,
// verbatim (measured 113.6 us; total 195.8 us). Fits in 16.6 MB workspace.
// ---------------------------------------------------------------------------
__global__ __launch_bounds__(512, 2) void pass2_full(
    const unsigned short* __restrict__ Qt,
    const unsigned short* __restrict__ Kt,
    const unsigned short* __restrict__ xb,
    const unsigned short* __restrict__ pwb,
    const float* __restrict__ x,
    float* __restrict__ out)
{
  __shared__ __align__(16) unsigned char SMEM[51968];
  float          (*S_lds)[132] = reinterpret_cast<float(*)[132]>(SMEM);
  unsigned short (*P_lds)[136] = reinterpret_cast<unsigned short(*)[136]>(SMEM + 33792);
  float* row_m     = reinterpret_cast<float*>(SMEM + 51200);
  float* row_l     = reinterpret_cast<float*>(SMEM + 51456);
  float* row_alpha = reinterpret_cast<float*>(SMEM + 51712);

  const int t    = threadIdx.x;
  const int id   = blockIdx.x;
  const int xcd  = id & 7;
  const int n    = xcd >> 1;
  const int s0   = ((id >> 3) * 2 + (xcd & 1)) * 64;
  const int w    = t >> 6;
  const int lane = t & 63;
  const int q    = lane >> 4;
  const int mr   = lane & 15;

  if (t < 64) { row_m[t] = -INFINITY; row_l[t] = 0.f; }

  bfrag qa[4][4];
  #pragma unroll
  for (int ms = 0; ms < 4; ++ms) {
    const bfrag* rp = reinterpret_cast<const bfrag*>(
        Qt + ((size_t)n * SS + s0 + ms * 16 + mr) * EE);
    #pragma unroll
    for (int k = 0; k < 4; ++k) qa[ms][k] = rp[k * 4 + q];
  }

  f32x4 o_acc[4][2];
  #pragma unroll
  for (int ms = 0; ms < 4; ++ms)
    #pragma unroll
    for (int nt = 0; nt < 2; ++nt) o_acc[ms][nt] = (f32x4){0.f, 0.f, 0.f, 0.f};

  bfrag kb[4];
  {
    const bfrag* rp = reinterpret_cast<const bfrag*>(
        Kt + ((size_t)n * SS + w * 16 + mr) * EE);
    #pragma unroll
    for (int k = 0; k < 4; ++k) kb[k] = rp[k * 4 + q];
  }

  for (int t0 = 0; t0 < SS; t0 += 128) {
    bfrag vb[4][2];
    #pragma unroll
    for (int nt = 0; nt < 2; ++nt) {
      const int c = w * 32 + nt * 16 + mr;
      const bfrag* vp = reinterpret_cast<const bfrag*>(
          xb + ((size_t)n * CH + c) * SS + t0);
      #pragma unroll
      for (int kk = 0; kk < 4; ++kk) vb[kk][nt] = vp[kk * 4 + q];
    }

    #pragma unroll
    for (int ms = 0; ms < 4; ++ms) {
      f32x4 acc = {0.f, 0.f, 0.f, 0.f};
      #pragma unroll
      for (int k = 0; k < 4; ++k)
        acc = __builtin_amdgcn_mfma_f32_16x16x32_bf16(qa[ms][k], kb[k], acc, 0, 0, 0);
      #pragma unroll
      for (int i = 0; i < 4; ++i)
        S_lds[ms * 16 + q * 4 + i][w * 16 + mr] = acc[i];
    }
    lds_barrier();

    {
      const int t1 = t0 + 128;
      if (t1 < SS) {
        const bfrag* rp = reinterpret_cast<const bfrag*>(
            Kt + ((size_t)n * SS + t1 + w * 16 + mr) * EE);
        #pragma unroll
        for (int k = 0; k < 4; ++k) kb[k] = rp[k * 4 + q];
      }
    }

    {
      const int r  = t >> 3;
      const int cg = t & 7;
      const float4* srow = reinterpret_cast<const float4*>(&S_lds[r][cg * 16]);
      float4 v0 = srow[0], v1 = srow[1], v2 = srow[2], v3 = srow[3];
      float vmax = fmaxf(fmaxf(fmaxf(v0.x, v0.y), fmaxf(v0.z, v0.w)),
                         fmaxf(fmaxf(v1.x, v1.y), fmaxf(v1.z, v1.w)));
      vmax = fmaxf(vmax, fmaxf(fmaxf(fmaxf(v2.x, v2.y), fmaxf(v2.z, v2.w)),
                               fmaxf(fmaxf(v3.x, v3.y), fmaxf(v3.z, v3.w))));
      vmax = fmaxf(vmax, __shfl_xor(vmax, 1, 8));
      vmax = fmaxf(vmax, __shfl_xor(vmax, 2, 8));
      vmax = fmaxf(vmax, __shfl_xor(vmax, 4, 8));
      const float m_old = row_m[r];
      const float m_new = fmaxf(m_old, vmax);

      float p[16];
      p[0]=__expf(v0.x-m_new); p[1]=__expf(v0.y-m_new); p[2]=__expf(v0.z-m_new); p[3]=__expf(v0.w-m_new);
      p[4]=__expf(v1.x-m_new); p[5]=__expf(v1.y-m_new); p[6]=__expf(v1.z-m_new); p[7]=__expf(v1.w-m_new);
      p[8]=__expf(v2.x-m_new); p[9]=__expf(v2.y-m_new); p[10]=__expf(v2.z-m_new); p[11]=__expf(v2.w-m_new);
      p[12]=__expf(v3.x-m_new); p[13]=__expf(v3.y-m_new); p[14]=__expf(v3.z-m_new); p[15]=__expf(v3.w-m_new);
      float sum = 0.f;
      u16x8 pk0, pk1;
      #pragma unroll
      for (int j = 0; j < 8; ++j) { sum += p[j];     pk0[j] = f2bf(p[j]); }
      #pragma unroll
      for (int j = 0; j < 8; ++j) { sum += p[8 + j]; pk1[j] = f2bf(p[8 + j]); }
      *reinterpret_cast<u16x8*>(&P_lds[r][cg * 16])     = pk0;
      *reinterpret_cast<u16x8*>(&P_lds[r][cg * 16 + 8]) = pk1;
      sum += __shfl_xor(sum, 1, 8);
      sum += __shfl_xor(sum, 2, 8);
      sum += __shfl_xor(sum, 4, 8);
      if (cg == 0) {
        const float al = __expf(m_old - m_new);
        row_alpha[r] = al;
        row_m[r]     = m_new;
        row_l[r]     = row_l[r] * al + sum;
      }
    }
    lds_barrier();

    #pragma unroll
    for (int ms = 0; ms < 4; ++ms) {
      float al[4];
      #pragma unroll
      for (int i = 0; i < 4; ++i) al[i] = row_alpha[ms * 16 + q * 4 + i];
      #pragma unroll
      for (int nt = 0; nt < 2; ++nt)
        #pragma unroll
        for (int i = 0; i < 4; ++i) o_acc[ms][nt][i] *= al[i];
    }

    #pragma unroll
    for (int kk = 0; kk < 4; ++kk) {
      bfrag pa[4];
      #pragma unroll
      for (int ms = 0; ms < 4; ++ms)
        pa[ms] = reinterpret_cast<const bfrag*>(&P_lds[ms * 16 + mr][0])[kk * 4 + q];
      #pragma unroll
      for (int nt = 0; nt < 2; ++nt)
        #pragma unroll
        for (int ms = 0; ms < 4; ++ms)
          o_acc[ms][nt] = __builtin_amdgcn_mfma_f32_16x16x32_bf16(
              pa[ms], vb[kk][nt], o_acc[ms][nt], 0, 0, 0);
    }
  }

  __syncthreads();
  unsigned short (*Y_lds)[CH + 8] =
      reinterpret_cast<unsigned short(*)[CH + 8]>(SMEM);

  #pragma unroll
  for (int ms = 0; ms < 4; ++ms) {
    float inv[4];
    #pragma unroll
    for (int i = 0; i < 4; ++i) inv[i] = 1.0f / row_l[ms * 16 + q * 4 + i];
    #pragma unroll
    for (int nt = 0; nt < 2; ++nt) {
      const int c = w * 32 + nt * 16 + mr;
      #pragma unroll
      for (int i = 0; i < 4; ++i)
        Y_lds[ms * 16 + q * 4 + i][c] = f2bf(o_acc[ms][nt][i] * inv[i]);
    }
  }
  __syncthreads();

  #pragma unroll
  for (int ot = 0; ot < 2; ++ot) {
    const int o0 = w * 32 + ot * 16;
    bfrag a[8];
    {
      const bfrag* ap = reinterpret_cast<const bfrag*>(pwb + (o0 + mr) * CH);
      #pragma unroll
      for (int k = 0; k < 8; ++k) a[k] = ap[k * 4 + q];
    }
    #pragma unroll
    for (int st = 0; st < 4; ++st) {
      f32x4 acc = {0.f, 0.f, 0.f, 0.f};
      const bfrag* bp = reinterpret_cast<const bfrag*>(&Y_lds[st * 16 + mr][0]);
      #pragma unroll
      for (int k = 0; k < 8; ++k)
        acc = __builtin_amdgcn_mfma_f32_16x16x32_bf16(a[k], bp[k * 4 + q], acc, 0, 0, 0);
      #pragma unroll
      for (int i = 0; i < 4; ++i) {
        const int o = o0 + q * 4 + i;
        const int s = s0 + st * 16 + mr;
        const size_t idx = ((size_t)n * CH + o) * SS + s;
        out[idx] = x[idx] + acc[i];
      }
    }
  }
}

// ---------------------------------------------------------------------------
extern "C" void kernel_launch(void* const* d_in, const int* in_sizes, int n_in,
                              void* d_out, int out_size, void* d_ws, size_t ws_size,
                              hipStream_t stream) {
  const float* x   = (const float*)d_in[0];
  const float* thw = (const float*)d_in[1];
  const float* phw = (const float*)d_in[2];
  const float* pw  = (const float*)d_in[3];
  float* out = (float*)d_out;

  unsigned short* xb   = (unsigned short*)d_ws;               // 8 MB
  unsigned short* Qt   = xb + (size_t)NB * CH * SS;           // 4 MB
  unsigned short* Kt   = Qt + (size_t)NB * SS * EE;           // 4 MB
  unsigned short* thwb = Kt + (size_t)NB * SS * EE;           // 64 KB
  unsigned short* phwb = thwb + EE * CH;                      // 64 KB
  unsigned short* pwb  = phwb + EE * CH;                      // 128 KB
  float*          ML   = (float*)(pwb + CH * CH);             // 512 KB (512p x 256)
  _Float16*       Opart = (_Float16*)(ML + (size_t)512 * 256);

  // strict gating: Opart = 512 partials x 128 x 256 fp16 = 33.55 MB.
  // Total need = 17,825,792 + 33,554,432; r7 proved ws >= 50,855,936 but ML
  // grew 256 KB, so gate on the exact new requirement and fall back if short.
  const size_t opart_off  = (size_t)((char*)Opart - (char*)d_ws);
  const size_t opart_bytes = (size_t)512 * 128 * 256 * 2;
  const int fits = ws_size >= opart_off + opart_bytes;

  const int nw4 = EE * CH / 4;
  const int np4 = CH * CH / 4;
  const int totw4 = 2 * nw4 + np4;
  cvt_w<<<(totw4 + 255) / 256, 256, 0, stream>>>(thw, phw, pw, thwb, phwb, pwb);

  pass1_qk<<<dim3(SS / 64, NB), 512, 0, stream>>>(x, thwb, phwb, xb, Qt, Kt);

  if (fits) {
    pass2a<<<dim3(512), 512, 0, stream>>>(Qt, Kt, xb, Opart, ML);
    pass2b<<<dim3(256), 512, 0, stream>>>(Opart, ML, pwb, x, out);
  } else {
    pass2_full<<<dim3(NB * SS / 64), 512, 0, stream>>>(Qt, Kt, xb, pwb, x, out);
  }
}

// Round 10
// 424.143 us; speedup vs baseline: 1.0039x; 1.0039x over previous
//
#include <hip/hip_runtime.h>
#include <cstdint>
#include <cstddef>

#define NB 4
#define CH 256
#define SS 4096
#define EE 128
#define QSCALE 0.08838834764831845f /* 1/sqrt(128) */

typedef __attribute__((ext_vector_type(8))) short bfrag;          // 8 bf16 = 4 VGPR
typedef __attribute__((ext_vector_type(8))) unsigned short u16x8; // 16B ld/st
typedef __attribute__((ext_vector_type(8))) _Float16 h16x8;       // 16B fp16
typedef __attribute__((ext_vector_type(4))) float f32x4;          // MFMA acc

__device__ __forceinline__ unsigned short f2bf(float f) {
  union { float f; unsigned int u; } v; v.f = f;
  unsigned int u = v.u;
  unsigned int r = u + 0x7FFFu + ((u >> 16) & 1u);  // RNE
  return (unsigned short)(r >> 16);
}
__device__ __forceinline__ float bf2f(unsigned short u) {
  union { unsigned int u; float f; } v; v.u = ((unsigned int)u) << 16;
  return v.f;
}

// LDS-only barrier: waits DS ops, leaves global loads in flight.
__device__ __forceinline__ void lds_barrier() {
  asm volatile("s_waitcnt lgkmcnt(0)" ::: "memory");
  __builtin_amdgcn_s_barrier();
}

// ---------------------------------------------------------------------------
// Pass 0: weights-only fp32 -> bf16
// ---------------------------------------------------------------------------
__global__ __launch_bounds__(256) void cvt_w(
    const float* __restrict__ thw, const float* __restrict__ phw,
    const float* __restrict__ pw,
    unsigned short* __restrict__ thwb, unsigned short* __restrict__ phwb,
    unsigned short* __restrict__ pwb)
{
  const int nw4 = EE * CH / 4;   // 8192
  const int np4 = CH * CH / 4;   // 16384
  int i = blockIdx.x * 256 + threadIdx.x;
  const float* src; unsigned short* dst; int off;
  if      (i < nw4)           { src = thw; dst = thwb; off = i; }
  else if (i < 2 * nw4)       { src = phw; dst = phwb; off = i - nw4; }
  else if (i < 2 * nw4 + np4) { src = pw;  dst = pwb;  off = i - 2 * nw4; }
  else return;
  float4 v = reinterpret_cast<const float4*>(src)[off];
  ushort4 o;
  o.x = f2bf(v.x); o.y = f2bf(v.y); o.z = f2bf(v.z); o.w = f2bf(v.w);
  reinterpret_cast<ushort4*>(dst)[off] = o;
}

// ---------------------------------------------------------------------------
// Pass 1 (fused): x fp32->bf16 (xb byproduct) + theta/phi projections.
// ---------------------------------------------------------------------------
__global__ __launch_bounds__(512) void pass1_qk(
    const float* __restrict__ x,
    const unsigned short* __restrict__ thw,
    const unsigned short* __restrict__ phw,
    unsigned short* __restrict__ xb,
    unsigned short* __restrict__ Qt,
    unsigned short* __restrict__ Kt)
{
  __shared__ unsigned short xT[64][CH + 8];
  const int t  = threadIdx.x;
  const int n  = blockIdx.y;
  const int s0 = blockIdx.x * 64;

  {
    const int soff = (t & 15) * 4;
    const int c0   = t >> 4;           // 0..31
    #pragma unroll
    for (int ci = 0; ci < 8; ++ci) {
      const int c = c0 + ci * 32;
      const size_t rowoff = ((size_t)n * CH + c) * SS + s0;
      float4 v = reinterpret_cast<const float4*>(x + rowoff)[soff >> 2];
      ushort4 o;
      o.x = f2bf(v.x); o.y = f2bf(v.y); o.z = f2bf(v.z); o.w = f2bf(v.w);
      reinterpret_cast<ushort4*>(xb + rowoff)[soff >> 2] = o;
      xT[soff + 0][c] = o.x;
      xT[soff + 1][c] = o.y;
      xT[soff + 2][c] = o.z;
      xT[soff + 3][c] = o.w;
    }
  }
  __syncthreads();

  const int w    = t >> 6;        // 0..7
  const int lane = t & 63;
  const int q    = lane >> 4;
  const int mr   = lane & 15;
  const int wrow = (w & 3) * 16;
  const int half = w >> 2;        // 0: theta->Qt, 1: phi->Kt

  bfrag a[8];
  {
    const bfrag* rp = reinterpret_cast<const bfrag*>(&xT[wrow + mr][0]);
    #pragma unroll
    for (int k = 0; k < 8; ++k) a[k] = rp[k * 4 + q];
  }

  const unsigned short* wsel = half ? phw : thw;
  unsigned short*       osel = half ? Kt  : Qt;
  const float           sc   = half ? 1.0f : QSCALE;
  const bfrag* wp = reinterpret_cast<const bfrag*>(wsel);
  #pragma unroll
  for (int nt = 0; nt < 8; ++nt) {
    f32x4 acc = {0.f, 0.f, 0.f, 0.f};
    #pragma unroll
    for (int k = 0; k < 8; ++k) {
      bfrag b = wp[(nt * 16 + mr) * (CH / 8) + k * 4 + q];
      acc = __builtin_amdgcn_mfma_f32_16x16x32_bf16(a[k], b, acc, 0, 0, 0);
    }
    #pragma unroll
    for (int i = 0; i < 4; ++i) {
      const int srow = s0 + wrow + q * 4 + i;
      osel[((size_t)n * SS + srow) * EE + nt * 16 + mr] = f2bf(acc[i] * sc);
    }
  }
}

// ---------------------------------------------------------------------------
// Pass 2a (r10 = r9 minus the spill): partial flash attention, Q-tile 128,
// keys quartered (1024/block, 512 blocks), 2 blocks/CU (LDS 68 KB, regs
// capped 128 via launch_bounds(512,4)).
// r9's failure: the T14 K-prefetch kept 16 regs live across softmax+PV ->
// total ~140 > 128 cap -> scratch spill (WRITE 46 MB, MfmaUtil 6%).
// r10: K(i+1) is staged compactly AFTER PV (load -> ds_write -> barrier,
// transient regs only); live set = o_acc 64 + vb 16 + addressing ~= 115.
// The exposed K latency in the iter tail is covered by the co-resident block.
// ---------------------------------------------------------------------------
__global__ __launch_bounds__(512, 4) void pass2a(
    const unsigned short* __restrict__ Qt,
    const unsigned short* __restrict__ Kt,
    const unsigned short* __restrict__ xb,
    _Float16* __restrict__ Opart,
    float* __restrict__ ML)
{
  //   [0      .. 33792)  Q_lds u16[128][132]
  //   [33792  .. 51200)  SP    u16[128][68]   (S bf16, P in place)
  //   [51200  .. 68096)  K_lds u16[64][132]
  //   [68096  .. 69632)  row_m / row_l / row_alpha  f32[128] each
  __shared__ __align__(16) unsigned char SMEM[69632];
  unsigned short (*Q_lds)[132] = reinterpret_cast<unsigned short(*)[132]>(SMEM);
  unsigned short (*SP)[68]     = reinterpret_cast<unsigned short(*)[68]>(SMEM + 33792);
  unsigned short (*K_lds)[132] = reinterpret_cast<unsigned short(*)[132]>(SMEM + 51200);
  float* row_m     = reinterpret_cast<float*>(SMEM + 68096);
  float* row_l     = reinterpret_cast<float*>(SMEM + 68608);
  float* row_alpha = reinterpret_cast<float*>(SMEM + 69120);

  const int t       = threadIdx.x;
  const int id      = blockIdx.x;
  const int xcd     = id & 7;
  const int n       = xcd >> 1;                       // image pinned to XCD pair
  const int quarter = (xcd & 1) * 2 + ((id >> 3) & 1);
  const int qt      = id >> 4;                        // 0..31
  const int s0      = qt * 128;
  const int kq0     = quarter * 1024;

  const int w    = t >> 6;        // 0..7
  const int lane = t & 63;
  const int q    = lane >> 4;
  const int mr   = lane & 15;
  const int rb   = (w >> 2) * 64; // QK row-half of this wave
  const int c4   = w & 3;         // QK key-col block (16 keys)

  if (t < 128) { row_m[t] = -INFINITY; row_l[t] = 0.f; }

  // stage Q tile 128x128 (coalesced 64B/thread)
  {
    const int r  = t >> 2;
    const int j0 = (t & 3) * 4;
    const unsigned short* src = Qt + ((size_t)n * SS + s0 + r) * EE;
    #pragma unroll
    for (int j = 0; j < 4; ++j) {
      const int col = (j0 + j) * 8;
      *reinterpret_cast<u16x8*>(&Q_lds[r][col]) =
          *reinterpret_cast<const u16x8*>(src + col);
    }
  }
  // stage K tile 0 (64 keys x 128e, 32B/thread)
  {
    const int key = t >> 3, c = t & 7;
    const unsigned short* src = Kt + ((size_t)n * SS + kq0 + key) * EE;
    *reinterpret_cast<u16x8*>(&K_lds[key][c * 8]) =
        *reinterpret_cast<const u16x8*>(src + c * 8);
    *reinterpret_cast<u16x8*>(&K_lds[key][(c + 8) * 8]) =
        *reinterpret_cast<const u16x8*>(src + (c + 8) * 8);
  }

  f32x4 o_accA[4][2], o_accB[4][2];
  #pragma unroll
  for (int ms = 0; ms < 4; ++ms)
    #pragma unroll
    for (int nt = 0; nt < 2; ++nt) {
      o_accA[ms][nt] = (f32x4){0.f, 0.f, 0.f, 0.f};
      o_accB[ms][nt] = (f32x4){0.f, 0.f, 0.f, 0.f};
    }

  __syncthreads();

#define PV_HALF(OACC, RB)                                                    \
  do {                                                                       \
    _Pragma("unroll")                                                        \
    for (int ms = 0; ms < 4; ++ms) {                                         \
      float al[4];                                                           \
      _Pragma("unroll")                                                      \
      for (int i = 0; i < 4; ++i) al[i] = row_alpha[(RB) + ms*16 + q*4 + i]; \
      _Pragma("unroll")                                                      \
      for (int nt = 0; nt < 2; ++nt)                                         \
        _Pragma("unroll")                                                    \
        for (int i = 0; i < 4; ++i) OACC[ms][nt][i] *= al[i];                \
    }                                                                        \
    _Pragma("unroll")                                                        \
    for (int kk = 0; kk < 2; ++kk) {                                         \
      bfrag pa[4];                                                           \
      _Pragma("unroll")                                                      \
      for (int ms = 0; ms < 4; ++ms)                                         \
        pa[ms] = *reinterpret_cast<const bfrag*>(                            \
            &SP[(RB) + ms * 16 + mr][(kk * 4 + q) * 8]);                     \
      _Pragma("unroll")                                                      \
      for (int nt = 0; nt < 2; ++nt)                                         \
        _Pragma("unroll")                                                    \
        for (int ms = 0; ms < 4; ++ms)                                       \
          OACC[ms][nt] = __builtin_amdgcn_mfma_f32_16x16x32_bf16(            \
              pa[ms], vb[kk][nt], OACC[ms][nt], 0, 0, 0);                    \
    }                                                                        \
  } while (0)

  for (int t0 = 0; t0 < 1024; t0 += 64) {
    // ---- V fragments for THIS iter (in flight across both barriers) ----
    bfrag vb[2][2];
    #pragma unroll
    for (int nt = 0; nt < 2; ++nt) {
      const int c = w * 32 + nt * 16 + mr;
      const bfrag* vp = reinterpret_cast<const bfrag*>(
          xb + ((size_t)n * CH + c) * SS + kq0 + t0);
      vb[0][nt] = vp[q];
      vb[1][nt] = vp[4 + q];
    }

    // ---- QK^T: wave -> rows rb..rb+63 x keys c4*16..+15, S written bf16 ----
    {
      bfrag kb[4];
      #pragma unroll
      for (int k = 0; k < 4; ++k)
        kb[k] = *reinterpret_cast<const bfrag*>(
            &K_lds[c4 * 16 + mr][(k * 4 + q) * 8]);
      #pragma unroll
      for (int ms = 0; ms < 4; ++ms) {
        f32x4 acc = {0.f, 0.f, 0.f, 0.f};
        #pragma unroll
        for (int k = 0; k < 4; ++k) {
          bfrag aq = *reinterpret_cast<const bfrag*>(
              &Q_lds[rb + ms * 16 + mr][(k * 4 + q) * 8]);
          acc = __builtin_amdgcn_mfma_f32_16x16x32_bf16(aq, kb[k], acc, 0, 0, 0);
        }
        #pragma unroll
        for (int i = 0; i < 4; ++i)
          SP[rb + ms * 16 + q * 4 + i][c4 * 16 + mr] = f2bf(acc[i]);
      }
    }
    lds_barrier();   // S visible

    // ---- online softmax, P in place over S (4 lanes/row x 16 keys) ----
    {
      const int r  = t >> 2;
      const int cg = t & 3;
      u16x8 sv0 = *reinterpret_cast<const u16x8*>(&SP[r][cg * 16]);
      u16x8 sv1 = *reinterpret_cast<const u16x8*>(&SP[r][cg * 16 + 8]);
      float s[16];
      #pragma unroll
      for (int j = 0; j < 8; ++j) { s[j] = bf2f(sv0[j]); s[8 + j] = bf2f(sv1[j]); }
      float vmax = s[0];
      #pragma unroll
      for (int j = 1; j < 16; ++j) vmax = fmaxf(vmax, s[j]);
      vmax = fmaxf(vmax, __shfl_xor(vmax, 1, 4));
      vmax = fmaxf(vmax, __shfl_xor(vmax, 2, 4));
      const float m_old = row_m[r];
      const float m_new = fmaxf(m_old, vmax);
      float sum = 0.f;
      u16x8 pk0, pk1;
      #pragma unroll
      for (int j = 0; j < 8; ++j) {
        float p = __expf(s[j] - m_new); sum += p; pk0[j] = f2bf(p);
      }
      #pragma unroll
      for (int j = 0; j < 8; ++j) {
        float p = __expf(s[8 + j] - m_new); sum += p; pk1[j] = f2bf(p);
      }
      *reinterpret_cast<u16x8*>(&SP[r][cg * 16])     = pk0;
      *reinterpret_cast<u16x8*>(&SP[r][cg * 16 + 8]) = pk1;
      sum += __shfl_xor(sum, 1, 4);
      sum += __shfl_xor(sum, 2, 4);
      if (cg == 0) {
        const float al = __expf(m_old - m_new);   // exp(-inf)=0 on iter 0
        row_alpha[r] = al;
        row_m[r]     = m_new;
        row_l[r]     = row_l[r] * al + sum;
      }
    }
    lds_barrier();   // P + alpha visible

    // ---- rescale + PV (both row halves, this wave's 32 V cols) ----
    PV_HALF(o_accA, 0);
    PV_HALF(o_accB, 64);

    // ---- stage K(i+1) compactly: load -> write (transient regs only).
    //      All waves are past bar2, so QK reads of K_lds are long done. ----
    if (t0 + 64 < 1024) {
      const int key = t >> 3, c = t & 7;
      const unsigned short* src =
          Kt + ((size_t)n * SS + kq0 + t0 + 64 + key) * EE;
      u16x8 kr0 = *reinterpret_cast<const u16x8*>(src + c * 8);
      u16x8 kr1 = *reinterpret_cast<const u16x8*>(src + (c + 8) * 8);
      *reinterpret_cast<u16x8*>(&K_lds[key][c * 8])       = kr0;
      *reinterpret_cast<u16x8*>(&K_lds[key][(c + 8) * 8]) = kr1;
    }
    lds_barrier();   // K(i+1) visible; P consumed before next QK overwrite
  }

  // ---- epilogue: normalized fp16 partials + (m,l) ----
  const size_t p = ((size_t)(n * 32 + qt)) * 4 + quarter;

#define EPI_HALF(OACC, RB)                                                   \
  do {                                                                       \
    _Pragma("unroll")                                                        \
    for (int ms = 0; ms < 4; ++ms) {                                         \
      float inv[4];                                                          \
      _Pragma("unroll")                                                      \
      for (int i = 0; i < 4; ++i)                                            \
        inv[i] = 1.0f / row_l[(RB) + ms * 16 + q * 4 + i];                   \
      _Pragma("unroll")                                                      \
      for (int nt = 0; nt < 2; ++nt)                                         \
        _Pragma("unroll")                                                    \
        for (int i = 0; i < 4; ++i) {                                        \
          const size_t oi =                                                  \
              (p * 128 + (RB) + ms * 16 + q * 4 + i) * 256 +                 \
              w * 32 + nt * 16 + mr;                                         \
          Opart[oi] = (_Float16)(OACC[ms][nt][i] * inv[i]);                  \
        }                                                                    \
    }                                                                        \
  } while (0)

  EPI_HALF(o_accA, 0);
  EPI_HALF(o_accB, 64);
  if (t < 128) {
    ML[p * 256 + t * 2]     = row_m[t];
    ML[p * 256 + t * 2 + 1] = row_l[t];
  }
}

// ---------------------------------------------------------------------------
// Pass 2b: 4-way merge of key-quarter partials + projection + residual.
// ---------------------------------------------------------------------------
__global__ __launch_bounds__(512) void pass2b(
    const _Float16* __restrict__ Opart,
    const float* __restrict__ ML,
    const unsigned short* __restrict__ pwb,
    const float* __restrict__ x,
    float* __restrict__ out)
{
  __shared__ __align__(16) unsigned char SMEM[34816];
  unsigned short (*Y_lds)[CH + 8] =
      reinterpret_cast<unsigned short(*)[CH + 8]>(SMEM);   // 64*264*2 = 33792
  float (*W)[64] = reinterpret_cast<float(*)[64]>(SMEM + 33792);  // 4x64 f32

  const int t   = threadIdx.x;
  const int id  = blockIdx.x;
  const int n   = id >> 6;
  const int sub = id & 63;
  const int s0  = sub * 64;
  const int qt  = sub >> 1;
  const int rb  = (sub & 1) * 64;          // row range within the q-tile
  const size_t p0 = ((size_t)(n * 32 + qt)) * 4;

  if (t < 64) {
    float m[4], l[4];
    #pragma unroll
    for (int qi = 0; qi < 4; ++qi) {
      m[qi] = ML[(p0 + qi) * 256 + (rb + t) * 2];
      l[qi] = ML[(p0 + qi) * 256 + (rb + t) * 2 + 1];
    }
    const float mm = fmaxf(fmaxf(m[0], m[1]), fmaxf(m[2], m[3]));
    float e[4], se = 0.f;
    #pragma unroll
    for (int qi = 0; qi < 4; ++qi) { e[qi] = __expf(m[qi] - mm) * l[qi]; se += e[qi]; }
    const float iL = 1.0f / se;
    #pragma unroll
    for (int qi = 0; qi < 4; ++qi) W[qi][t] = e[qi] * iL;
  }
  __syncthreads();

  // merge partials -> Y_lds (bf16)
  {
    const int r = t >> 3;
    #pragma unroll
    for (int seg = 0; seg < 4; ++seg) {
      const int c0 = (t & 7) * 8 + seg * 64;
      float acc[8] = {0.f, 0.f, 0.f, 0.f, 0.f, 0.f, 0.f, 0.f};
      #pragma unroll
      for (int qi = 0; qi < 4; ++qi) {
        h16x8 hv = *reinterpret_cast<const h16x8*>(
            Opart + ((p0 + qi) * 128 + rb + r) * 256 + c0);
        const float wq = W[qi][r];
        #pragma unroll
        for (int j = 0; j < 8; ++j) acc[j] += (float)hv[j] * wq;
      }
      u16x8 y;
      #pragma unroll
      for (int j = 0; j < 8; ++j) y[j] = f2bf(acc[j]);
      *reinterpret_cast<u16x8*>(&Y_lds[r][c0]) = y;
    }
  }
  __syncthreads();

  // projection + residual: wave w -> output rows o = w*32 .. w*32+31
  const int w    = t >> 6;
  const int lane = t & 63;
  const int q    = lane >> 4;
  const int mr   = lane & 15;
  #pragma unroll
  for (int ot = 0; ot < 2; ++ot) {
    const int o0 = w * 32 + ot * 16;
    bfrag a[8];
    {
      const bfrag* ap = reinterpret_cast<const bfrag*>(pwb + (o0 + mr) * CH);
      #pragma unroll
      for (int k = 0; k < 8; ++k) a[k] = ap[k * 4 + q];
    }
    #pragma unroll
    for (int st = 0; st < 4; ++st) {
      f32x4 acc = {0.f, 0.f, 0.f, 0.f};
      const bfrag* bp = reinterpret_cast<const bfrag*>(&Y_lds[st * 16 + mr][0]);
      #pragma unroll
      for (int k = 0; k < 8; ++k)
        acc = __builtin_amdgcn_mfma_f32_16x16x32_bf16(a[k], bp[k * 4 + q], acc, 0, 0, 0);
      #pragma unroll
      for (int i = 0; i < 4; ++i) {
        const int o = o0 + q * 4 + i;
        const int s = s0 + st * 16 + mr;
        const size_t idx = ((size_t)n * CH + o) * SS + s;
        out[idx] = x[idx] + acc[i];
      }
    }
  }
}

// ---------------------------------------------------------------------------
// Fallback (ws too small for partials): round-5 fused full-key kernel,
// verbatim (measured 113.6 us; total 195.8 us). Fits in 16.6 MB workspace.
// ---------------------------------------------------------------------------
__global__ __launch_bounds__(512, 2) void pass2_full(
    const unsigned short* __restrict__ Qt,
    const unsigned short* __restrict__ Kt,
    const unsigned short* __restrict__ xb,
    const unsigned short* __restrict__ pwb,
    const float* __restrict__ x,
    float* __restrict__ out)
{
  __shared__ __align__(16) unsigned char SMEM[51968];
  float          (*S_lds)[132] = reinterpret_cast<float(*)[132]>(SMEM);
  unsigned short (*P_lds)[136] = reinterpret_cast<unsigned short(*)[136]>(SMEM + 33792);
  float* row_m     = reinterpret_cast<float*>(SMEM + 51200);
  float* row_l     = reinterpret_cast<float*>(SMEM + 51456);
  float* row_alpha = reinterpret_cast<float*>(SMEM + 51712);

  const int t    = threadIdx.x;
  const int id   = blockIdx.x;
  const int xcd  = id & 7;
  const int n    = xcd >> 1;
  const int s0   = ((id >> 3) * 2 + (xcd & 1)) * 64;
  const int w    = t >> 6;
  const int lane = t & 63;
  const int q    = lane >> 4;
  const int mr   = lane & 15;

  if (t < 64) { row_m[t] = -INFINITY; row_l[t] = 0.f; }

  bfrag qa[4][4];
  #pragma unroll
  for (int ms = 0; ms < 4; ++ms) {
    const bfrag* rp = reinterpret_cast<const bfrag*>(
        Qt + ((size_t)n * SS + s0 + ms * 16 + mr) * EE);
    #pragma unroll
    for (int k = 0; k < 4; ++k) qa[ms][k] = rp[k * 4 + q];
  }

  f32x4 o_acc[4][2];
  #pragma unroll
  for (int ms = 0; ms < 4; ++ms)
    #pragma unroll
    for (int nt = 0; nt < 2; ++nt) o_acc[ms][nt] = (f32x4){0.f, 0.f, 0.f, 0.f};

  bfrag kb[4];
  {
    const bfrag* rp = reinterpret_cast<const bfrag*>(
        Kt + ((size_t)n * SS + w * 16 + mr) * EE);
    #pragma unroll
    for (int k = 0; k < 4; ++k) kb[k] = rp[k * 4 + q];
  }

  for (int t0 = 0; t0 < SS; t0 += 128) {
    bfrag vb[4][2];
    #pragma unroll
    for (int nt = 0; nt < 2; ++nt) {
      const int c = w * 32 + nt * 16 + mr;
      const bfrag* vp = reinterpret_cast<const bfrag*>(
          xb + ((size_t)n * CH + c) * SS + t0);
      #pragma unroll
      for (int kk = 0; kk < 4; ++kk) vb[kk][nt] = vp[kk * 4 + q];
    }

    #pragma unroll
    for (int ms = 0; ms < 4; ++ms) {
      f32x4 acc = {0.f, 0.f, 0.f, 0.f};
      #pragma unroll
      for (int k = 0; k < 4; ++k)
        acc = __builtin_amdgcn_mfma_f32_16x16x32_bf16(qa[ms][k], kb[k], acc, 0, 0, 0);
      #pragma unroll
      for (int i = 0; i < 4; ++i)
        S_lds[ms * 16 + q * 4 + i][w * 16 + mr] = acc[i];
    }
    lds_barrier();

    {
      const int t1 = t0 + 128;
      if (t1 < SS) {
        const bfrag* rp = reinterpret_cast<const bfrag*>(
            Kt + ((size_t)n * SS + t1 + w * 16 + mr) * EE);
        #pragma unroll
        for (int k = 0; k < 4; ++k) kb[k] = rp[k * 4 + q];
      }
    }

    {
      const int r  = t >> 3;
      const int cg = t & 7;
      const float4* srow = reinterpret_cast<const float4*>(&S_lds[r][cg * 16]);
      float4 v0 = srow[0], v1 = srow[1], v2 = srow[2], v3 = srow[3];
      float vmax = fmaxf(fmaxf(fmaxf(v0.x, v0.y), fmaxf(v0.z, v0.w)),
                         fmaxf(fmaxf(v1.x, v1.y), fmaxf(v1.z, v1.w)));
      vmax = fmaxf(vmax, fmaxf(fmaxf(fmaxf(v2.x, v2.y), fmaxf(v2.z, v2.w)),
                               fmaxf(fmaxf(v3.x, v3.y), fmaxf(v3.z, v3.w))));
      vmax = fmaxf(vmax, __shfl_xor(vmax, 1, 8));
      vmax = fmaxf(vmax, __shfl_xor(vmax, 2, 8));
      vmax = fmaxf(vmax, __shfl_xor(vmax, 4, 8));
      const float m_old = row_m[r];
      const float m_new = fmaxf(m_old, vmax);

      float p[16];
      p[0]=__expf(v0.x-m_new); p[1]=__expf(v0.y-m_new); p[2]=__expf(v0.z-m_new); p[3]=__expf(v0.w-m_new);
      p[4]=__expf(v1.x-m_new); p[5]=__expf(v1.y-m_new); p[6]=__expf(v1.z-m_new); p[7]=__expf(v1.w-m_new);
      p[8]=__expf(v2.x-m_new); p[9]=__expf(v2.y-m_new); p[10]=__expf(v2.z-m_new); p[11]=__expf(v2.w-m_new);
      p[12]=__expf(v3.x-m_new); p[13]=__expf(v3.y-m_new); p[14]=__expf(v3.z-m_new); p[15]=__expf(v3.w-m_new);
      float sum = 0.f;
      u16x8 pk0, pk1;
      #pragma unroll
      for (int j = 0; j < 8; ++j) { sum += p[j];     pk0[j] = f2bf(p[j]); }
      #pragma unroll
      for (int j = 0; j < 8; ++j) { sum += p[8 + j]; pk1[j] = f2bf(p[8 + j]); }
      *reinterpret_cast<u16x8*>(&P_lds[r][cg * 16])     = pk0;
      *reinterpret_cast<u16x8*>(&P_lds[r][cg * 16 + 8]) = pk1;
      sum += __shfl_xor(sum, 1, 8);
      sum += __shfl_xor(sum, 2, 8);
      sum += __shfl_xor(sum, 4, 8);
      if (cg == 0) {
        const float al = __expf(m_old - m_new);
        row_alpha[r] = al;
        row_m[r]     = m_new;
        row_l[r]     = row_l[r] * al + sum;
      }
    }
    lds_barrier();

    #pragma unroll
    for (int ms = 0; ms < 4; ++ms) {
      float al[4];
      #pragma unroll
      for (int i = 0; i < 4; ++i) al[i] = row_alpha[ms * 16 + q * 4 + i];
      #pragma unroll
      for (int nt = 0; nt < 2; ++nt)
        #pragma unroll
        for (int i = 0; i < 4; ++i) o_acc[ms][nt][i] *= al[i];
    }

    #pragma unroll
    for (int kk = 0; kk < 4; ++kk) {
      bfrag pa[4];
      #pragma unroll
      for (int ms = 0; ms < 4; ++ms)
        pa[ms] = reinterpret_cast<const bfrag*>(&P_lds[ms * 16 + mr][0])[kk * 4 + q];
      #pragma unroll
      for (int nt = 0; nt < 2; ++nt)
        #pragma unroll
        for (int ms = 0; ms < 4; ++ms)
          o_acc[ms][nt] = __builtin_amdgcn_mfma_f32_16x16x32_bf16(
              pa[ms], vb[kk][nt], o_acc[ms][nt], 0, 0, 0);
    }
  }

  __syncthreads();
  unsigned short (*Y_lds)[CH + 8] =
      reinterpret_cast<unsigned short(*)[CH + 8]>(SMEM);

  #pragma unroll
  for (int ms = 0; ms < 4; ++ms) {
    float inv[4];
    #pragma unroll
    for (int i = 0; i < 4; ++i) inv[i] = 1.0f / row_l[ms * 16 + q * 4 + i];
    #pragma unroll
    for (int nt = 0; nt < 2; ++nt) {
      const int c = w * 32 + nt * 16 + mr;
      #pragma unroll
      for (int i = 0; i < 4; ++i)
        Y_lds[ms * 16 + q * 4 + i][c] = f2bf(o_acc[ms][nt][i] * inv[i]);
    }
  }
  __syncthreads();

  #pragma unroll
  for (int ot = 0; ot < 2; ++ot) {
    const int o0 = w * 32 + ot * 16;
    bfrag a[8];
    {
      const bfrag* ap = reinterpret_cast<const bfrag*>(pwb + (o0 + mr) * CH);
      #pragma unroll
      for (int k = 0; k < 8; ++k) a[k] = ap[k * 4 + q];
    }
    #pragma unroll
    for (int st = 0; st < 4; ++st) {
      f32x4 acc = {0.f, 0.f, 0.f, 0.f};
      const bfrag* bp = reinterpret_cast<const bfrag*>(&Y_lds[st * 16 + mr][0]);
      #pragma unroll
      for (int k = 0; k < 8; ++k)
        acc = __builtin_amdgcn_mfma_f32_16x16x32_bf16(a[k], bp[k * 4 + q], acc, 0, 0, 0);
      #pragma unroll
      for (int i = 0; i < 4; ++i) {
        const int o = o0 + q * 4 + i;
        const int s = s0 + st * 16 + mr;
        const size_t idx = ((size_t)n * CH + o) * SS + s;
        out[idx] = x[idx] + acc[i];
      }
    }
  }
}

// ---------------------------------------------------------------------------
extern "C" void kernel_launch(void* const* d_in, const int* in_sizes, int n_in,
                              void* d_out, int out_size, void* d_ws, size_t ws_size,
                              hipStream_t stream) {
  const float* x   = (const float*)d_in[0];
  const float* thw = (const float*)d_in[1];
  const float* phw = (const float*)d_in[2];
  const float* pw  = (const float*)d_in[3];
  float* out = (float*)d_out;

  unsigned short* xb   = (unsigned short*)d_ws;               // 8 MB
  unsigned short* Qt   = xb + (size_t)NB * CH * SS;           // 4 MB
  unsigned short* Kt   = Qt + (size_t)NB * SS * EE;           // 4 MB
  unsigned short* thwb = Kt + (size_t)NB * SS * EE;           // 64 KB
  unsigned short* phwb = thwb + EE * CH;                      // 64 KB
  unsigned short* pwb  = phwb + EE * CH;                      // 128 KB
  float*          ML   = (float*)(pwb + CH * CH);             // 512 KB (512p x 256)
  _Float16*       Opart = (_Float16*)(ML + (size_t)512 * 256);

  // strict gating: Opart = 512 partials x 128 x 256 fp16 = 33.55 MB.
  const size_t opart_off  = (size_t)((char*)Opart - (char*)d_ws);
  const size_t opart_bytes = (size_t)512 * 128 * 256 * 2;
  const int fits = ws_size >= opart_off + opart_bytes;

  const int nw4 = EE * CH / 4;
  const int np4 = CH * CH / 4;
  const int totw4 = 2 * nw4 + np4;
  cvt_w<<<(totw4 + 255) / 256, 256, 0, stream>>>(thw, phw, pw, thwb, phwb, pwb);

  pass1_qk<<<dim3(SS / 64, NB), 512, 0, stream>>>(x, thwb, phwb, xb, Qt, Kt);

  if (fits) {
    pass2a<<<dim3(512), 512, 0, stream>>>(Qt, Kt, xb, Opart, ML);
    pass2b<<<dim3(256), 512, 0, stream>>>(Opart, ML, pwb, x, out);
  } else {
    pass2_full<<<dim3(NB * SS / 64), 512, 0, stream>>>(Qt, Kt, xb, pwb, x, out);
  }
}

// Round 11
// 330.469 us; speedup vs baseline: 1.2885x; 1.2835x over previous
//
#include <hip/hip_runtime.h>
#include <cstdint>
#include <cstddef>

#define NB 4
#define CH 256
#define SS 4096
#define EE 128
#define QSCALE 0.08838834764831845f /* 1/sqrt(128) */

typedef __attribute__((ext_vector_type(8))) short bfrag;          // 8 bf16 = 4 VGPR
typedef __attribute__((ext_vector_type(8))) unsigned short u16x8; // 16B ld/st
typedef __attribute__((ext_vector_type(8))) _Float16 h16x8;       // 16B fp16
typedef __attribute__((ext_vector_type(4))) float f32x4;          // MFMA acc

__device__ __forceinline__ unsigned short f2bf(float f) {
  union { float f; unsigned int u; } v; v.f = f;
  unsigned int u = v.u;
  unsigned int r = u + 0x7FFFu + ((u >> 16) & 1u);  // RNE
  return (unsigned short)(r >> 16);
}
__device__ __forceinline__ float bf2f(unsigned short u) {
  union { unsigned int u; float f; } v; v.u = ((unsigned int)u) << 16;
  return v.f;
}

// LDS-only barrier: waits DS ops, leaves global loads in flight.
__device__ __forceinline__ void lds_barrier() {
  asm volatile("s_waitcnt lgkmcnt(0)" ::: "memory");
  __builtin_amdgcn_s_barrier();
}

// ---------------------------------------------------------------------------
// Pass 0: weights-only fp32 -> bf16
// ---------------------------------------------------------------------------
__global__ __launch_bounds__(256) void cvt_w(
    const float* __restrict__ thw, const float* __restrict__ phw,
    const float* __restrict__ pw,
    unsigned short* __restrict__ thwb, unsigned short* __restrict__ phwb,
    unsigned short* __restrict__ pwb)
{
  const int nw4 = EE * CH / 4;   // 8192
  const int np4 = CH * CH / 4;   // 16384
  int i = blockIdx.x * 256 + threadIdx.x;
  const float* src; unsigned short* dst; int off;
  if      (i < nw4)           { src = thw; dst = thwb; off = i; }
  else if (i < 2 * nw4)       { src = phw; dst = phwb; off = i - nw4; }
  else if (i < 2 * nw4 + np4) { src = pw;  dst = pwb;  off = i - 2 * nw4; }
  else return;
  float4 v = reinterpret_cast<const float4*>(src)[off];
  ushort4 o;
  o.x = f2bf(v.x); o.y = f2bf(v.y); o.z = f2bf(v.z); o.w = f2bf(v.w);
  reinterpret_cast<ushort4*>(dst)[off] = o;
}

// ---------------------------------------------------------------------------
// Pass 1 (fused): x fp32->bf16 (xb byproduct) + theta/phi projections.
// ---------------------------------------------------------------------------
__global__ __launch_bounds__(512) void pass1_qk(
    const float* __restrict__ x,
    const unsigned short* __restrict__ thw,
    const unsigned short* __restrict__ phw,
    unsigned short* __restrict__ xb,
    unsigned short* __restrict__ Qt,
    unsigned short* __restrict__ Kt)
{
  __shared__ unsigned short xT[64][CH + 8];
  const int t  = threadIdx.x;
  const int n  = blockIdx.y;
  const int s0 = blockIdx.x * 64;

  {
    const int soff = (t & 15) * 4;
    const int c0   = t >> 4;           // 0..31
    #pragma unroll
    for (int ci = 0; ci < 8; ++ci) {
      const int c = c0 + ci * 32;
      const size_t rowoff = ((size_t)n * CH + c) * SS + s0;
      float4 v = reinterpret_cast<const float4*>(x + rowoff)[soff >> 2];
      ushort4 o;
      o.x = f2bf(v.x); o.y = f2bf(v.y); o.z = f2bf(v.z); o.w = f2bf(v.w);
      reinterpret_cast<ushort4*>(xb + rowoff)[soff >> 2] = o;
      xT[soff + 0][c] = o.x;
      xT[soff + 1][c] = o.y;
      xT[soff + 2][c] = o.z;
      xT[soff + 3][c] = o.w;
    }
  }
  __syncthreads();

  const int w    = t >> 6;        // 0..7
  const int lane = t & 63;
  const int q    = lane >> 4;
  const int mr   = lane & 15;
  const int wrow = (w & 3) * 16;
  const int half = w >> 2;        // 0: theta->Qt, 1: phi->Kt

  bfrag a[8];
  {
    const bfrag* rp = reinterpret_cast<const bfrag*>(&xT[wrow + mr][0]);
    #pragma unroll
    for (int k = 0; k < 8; ++k) a[k] = rp[k * 4 + q];
  }

  const unsigned short* wsel = half ? phw : thw;
  unsigned short*       osel = half ? Kt  : Qt;
  const float           sc   = half ? 1.0f : QSCALE;
  const bfrag* wp = reinterpret_cast<const bfrag*>(wsel);
  #pragma unroll
  for (int nt = 0; nt < 8; ++nt) {
    f32x4 acc = {0.f, 0.f, 0.f, 0.f};
    #pragma unroll
    for (int k = 0; k < 8; ++k) {
      bfrag b = wp[(nt * 16 + mr) * (CH / 8) + k * 4 + q];
      acc = __builtin_amdgcn_mfma_f32_16x16x32_bf16(a[k], b, acc, 0, 0, 0);
    }
    #pragma unroll
    for (int i = 0; i < 4; ++i) {
      const int srow = s0 + wrow + q * 4 + i;
      osel[((size_t)n * SS + srow) * EE + nt * 16 + mr] = f2bf(acc[i] * sc);
    }
  }
}

// ---------------------------------------------------------------------------
// Pass 2a (r11): partial flash attention with TWO INDEPENDENT BLOCKS PER CU
// AT FULL REGISTER BUDGET. 512 blocks x 256 threads (4 waves),
// launch_bounds(256,2): 2 blocks/CU = 8 waves/CU = 2 waves/SIMD -> 256
// regs/wave (r9/r10's famine was the (512,4) 128-reg cap: compiler fit by
// destroying ILP -> MfmaUtil 6%). Same TLP as r7's best; the delta is two
// independent barrier domains/CU so one block's softmax overlaps the other's
// MFMA phases. Q-tile 128, keys quartered (1024/block): traffic 384 MB.
// Per wave: QK = 8 row-frags x 16 key-cols (kb[4] regs, K never in LDS);
// PV = 64 output chans (vb[2][4]); o_acc[8][4]=128 regs. Q in LDS; S bf16
// in-place -> P (0-conflict, verified r9/r10). Live regs ~220 < 256.
// ---------------------------------------------------------------------------
__global__ __launch_bounds__(256, 2) void pass2a(
    const unsigned short* __restrict__ Qt,
    const unsigned short* __restrict__ Kt,
    const unsigned short* __restrict__ xb,
    _Float16* __restrict__ Opart,
    float* __restrict__ ML)
{
  //   [0      .. 33792)  Q_lds u16[128][132]
  //   [33792  .. 51200)  SP    u16[128][68]   (S bf16, P in place)
  //   [51200  .. 52736)  row_m / row_l / row_alpha  f32[128] each
  __shared__ __align__(16) unsigned char SMEM[52736];
  unsigned short (*Q_lds)[132] = reinterpret_cast<unsigned short(*)[132]>(SMEM);
  unsigned short (*SP)[68]     = reinterpret_cast<unsigned short(*)[68]>(SMEM + 33792);
  float* row_m     = reinterpret_cast<float*>(SMEM + 51200);
  float* row_l     = reinterpret_cast<float*>(SMEM + 51712);
  float* row_alpha = reinterpret_cast<float*>(SMEM + 52224);

  const int t       = threadIdx.x;   // 0..255
  const int id      = blockIdx.x;
  const int xcd     = id & 7;
  const int n       = xcd >> 1;                       // image pinned to XCD pair
  const int quarter = (xcd & 1) * 2 + ((id >> 3) & 1);
  const int qt      = id >> 4;                        // 0..31
  const int s0      = qt * 128;
  const int kq0     = quarter * 1024;

  const int w    = t >> 6;        // 0..3
  const int lane = t & 63;
  const int q    = lane >> 4;
  const int mr   = lane & 15;

  if (t < 128) { row_m[t] = -INFINITY; row_l[t] = 0.f; }

  // stage Q tile 128x128 (2 threads/row, 128B each, coalesced)
  {
    const int r  = t >> 1;
    const int j0 = (t & 1) * 8;
    const unsigned short* src = Qt + ((size_t)n * SS + s0 + r) * EE;
    #pragma unroll
    for (int j = 0; j < 8; ++j) {
      const int col = (j0 + j) * 8;
      *reinterpret_cast<u16x8*>(&Q_lds[r][col]) =
          *reinterpret_cast<const u16x8*>(src + col);
    }
  }

  f32x4 o_acc[8][4];
  #pragma unroll
  for (int ms = 0; ms < 8; ++ms)
    #pragma unroll
    for (int nt = 0; nt < 4; ++nt) o_acc[ms][nt] = (f32x4){0.f, 0.f, 0.f, 0.f};

  __syncthreads();   // Q + row init visible

  // K fragments for iter 0: wave w -> key rows kq0 + w*16 + mr
  bfrag kb[4];
  {
    const bfrag* rp = reinterpret_cast<const bfrag*>(
        Kt + ((size_t)n * SS + kq0 + w * 16 + mr) * EE);
    #pragma unroll
    for (int k = 0; k < 4; ++k) kb[k] = rp[k * 4 + q];
  }

  for (int t0 = 0; t0 < 1024; t0 += 64) {
    // ---- V fragments for THIS iter (in flight across barriers) ----
    bfrag vb[2][4];
    #pragma unroll
    for (int nt = 0; nt < 4; ++nt) {
      const int c = w * 64 + nt * 16 + mr;
      const bfrag* vp = reinterpret_cast<const bfrag*>(
          xb + ((size_t)n * CH + c) * SS + kq0 + t0);
      vb[0][nt] = vp[q];
      vb[1][nt] = vp[4 + q];
    }

    // ---- QK^T: wave w -> all 128 rows x key cols w*16..+15, S bf16 ----
    #pragma unroll
    for (int ms = 0; ms < 8; ++ms) {
      f32x4 acc = {0.f, 0.f, 0.f, 0.f};
      #pragma unroll
      for (int k = 0; k < 4; ++k) {
        bfrag aq = *reinterpret_cast<const bfrag*>(
            &Q_lds[ms * 16 + mr][(k * 4 + q) * 8]);
        acc = __builtin_amdgcn_mfma_f32_16x16x32_bf16(aq, kb[k], acc, 0, 0, 0);
      }
      #pragma unroll
      for (int i = 0; i < 4; ++i)
        SP[ms * 16 + q * 4 + i][w * 16 + mr] = f2bf(acc[i]);
    }
    lds_barrier();   // S visible

    // ---- prefetch K fragments for NEXT iter (16 regs, headroom now) ----
    if (t0 + 64 < 1024) {
      const bfrag* rp = reinterpret_cast<const bfrag*>(
          Kt + ((size_t)n * SS + kq0 + t0 + 64 + w * 16 + mr) * EE);
      #pragma unroll
      for (int k = 0; k < 4; ++k) kb[k] = rp[k * 4 + q];
    }

    // ---- online softmax, P in place over S (2 lanes/row x 32 keys) ----
    {
      const int r  = t >> 1;
      const int cg = t & 1;
      u16x8 sv0 = *reinterpret_cast<const u16x8*>(&SP[r][cg * 32]);
      u16x8 sv1 = *reinterpret_cast<const u16x8*>(&SP[r][cg * 32 + 8]);
      u16x8 sv2 = *reinterpret_cast<const u16x8*>(&SP[r][cg * 32 + 16]);
      u16x8 sv3 = *reinterpret_cast<const u16x8*>(&SP[r][cg * 32 + 24]);
      float vmax = bf2f(sv0[0]);
      #pragma unroll
      for (int j = 1; j < 8; ++j) vmax = fmaxf(vmax, bf2f(sv0[j]));
      #pragma unroll
      for (int j = 0; j < 8; ++j) vmax = fmaxf(vmax, bf2f(sv1[j]));
      #pragma unroll
      for (int j = 0; j < 8; ++j) vmax = fmaxf(vmax, bf2f(sv2[j]));
      #pragma unroll
      for (int j = 0; j < 8; ++j) vmax = fmaxf(vmax, bf2f(sv3[j]));
      vmax = fmaxf(vmax, __shfl_xor(vmax, 1, 2));
      const float m_old = row_m[r];
      const float m_new = fmaxf(m_old, vmax);
      float sum = 0.f;
      u16x8 pk;
      #pragma unroll
      for (int j = 0; j < 8; ++j) {
        float p = __expf(bf2f(sv0[j]) - m_new); sum += p; pk[j] = f2bf(p);
      }
      *reinterpret_cast<u16x8*>(&SP[r][cg * 32]) = pk;
      #pragma unroll
      for (int j = 0; j < 8; ++j) {
        float p = __expf(bf2f(sv1[j]) - m_new); sum += p; pk[j] = f2bf(p);
      }
      *reinterpret_cast<u16x8*>(&SP[r][cg * 32 + 8]) = pk;
      #pragma unroll
      for (int j = 0; j < 8; ++j) {
        float p = __expf(bf2f(sv2[j]) - m_new); sum += p; pk[j] = f2bf(p);
      }
      *reinterpret_cast<u16x8*>(&SP[r][cg * 32 + 16]) = pk;
      #pragma unroll
      for (int j = 0; j < 8; ++j) {
        float p = __expf(bf2f(sv3[j]) - m_new); sum += p; pk[j] = f2bf(p);
      }
      *reinterpret_cast<u16x8*>(&SP[r][cg * 32 + 24]) = pk;
      sum += __shfl_xor(sum, 1, 2);
      if (cg == 0) {
        const float al = __expf(m_old - m_new);   // exp(-inf)=0 on iter 0
        row_alpha[r] = al;
        row_m[r]     = m_new;
        row_l[r]     = row_l[r] * al + sum;
      }
    }
    lds_barrier();   // P + alpha visible

    // ---- rescale O, then O += P @ V (this wave's 64 V cols) ----
    #pragma unroll
    for (int ms = 0; ms < 8; ++ms) {
      float al[4];
      #pragma unroll
      for (int i = 0; i < 4; ++i) al[i] = row_alpha[ms * 16 + q * 4 + i];
      #pragma unroll
      for (int nt = 0; nt < 4; ++nt)
        #pragma unroll
        for (int i = 0; i < 4; ++i) o_acc[ms][nt][i] *= al[i];
    }

    #pragma unroll
    for (int kk = 0; kk < 2; ++kk) {
      bfrag pa[8];
      #pragma unroll
      for (int ms = 0; ms < 8; ++ms)
        pa[ms] = *reinterpret_cast<const bfrag*>(
            &SP[ms * 16 + mr][(kk * 4 + q) * 8]);
      #pragma unroll
      for (int nt = 0; nt < 4; ++nt)
        #pragma unroll
        for (int ms = 0; ms < 8; ++ms)
          o_acc[ms][nt] = __builtin_amdgcn_mfma_f32_16x16x32_bf16(
              pa[ms], vb[kk][nt], o_acc[ms][nt], 0, 0, 0);
    }
    lds_barrier();   // P consumed before next iter's QK overwrites SP
  }

  // ---- epilogue: normalized fp16 partials + (m,l) ----
  const size_t p = ((size_t)(n * 32 + qt)) * 4 + quarter;

  #pragma unroll
  for (int ms = 0; ms < 8; ++ms) {
    float inv[4];
    #pragma unroll
    for (int i = 0; i < 4; ++i)
      inv[i] = 1.0f / row_l[ms * 16 + q * 4 + i];
    #pragma unroll
    for (int nt = 0; nt < 4; ++nt)
      #pragma unroll
      for (int i = 0; i < 4; ++i) {
        const size_t oi = (p * 128 + ms * 16 + q * 4 + i) * 256 +
                          w * 64 + nt * 16 + mr;
        Opart[oi] = (_Float16)(o_acc[ms][nt][i] * inv[i]);
      }
  }
  if (t < 128) {
    ML[p * 256 + t * 2]     = row_m[t];
    ML[p * 256 + t * 2 + 1] = row_l[t];
  }
}

// ---------------------------------------------------------------------------
// Pass 2b: 4-way merge of key-quarter partials + projection + residual.
// (unchanged from r10, which passed)
// ---------------------------------------------------------------------------
__global__ __launch_bounds__(512) void pass2b(
    const _Float16* __restrict__ Opart,
    const float* __restrict__ ML,
    const unsigned short* __restrict__ pwb,
    const float* __restrict__ x,
    float* __restrict__ out)
{
  __shared__ __align__(16) unsigned char SMEM[34816];
  unsigned short (*Y_lds)[CH + 8] =
      reinterpret_cast<unsigned short(*)[CH + 8]>(SMEM);   // 64*264*2 = 33792
  float (*W)[64] = reinterpret_cast<float(*)[64]>(SMEM + 33792);  // 4x64 f32

  const int t   = threadIdx.x;
  const int id  = blockIdx.x;
  const int n   = id >> 6;
  const int sub = id & 63;
  const int s0  = sub * 64;
  const int qt  = sub >> 1;
  const int rb  = (sub & 1) * 64;          // row range within the q-tile
  const size_t p0 = ((size_t)(n * 32 + qt)) * 4;

  if (t < 64) {
    float m[4], l[4];
    #pragma unroll
    for (int qi = 0; qi < 4; ++qi) {
      m[qi] = ML[(p0 + qi) * 256 + (rb + t) * 2];
      l[qi] = ML[(p0 + qi) * 256 + (rb + t) * 2 + 1];
    }
    const float mm = fmaxf(fmaxf(m[0], m[1]), fmaxf(m[2], m[3]));
    float e[4], se = 0.f;
    #pragma unroll
    for (int qi = 0; qi < 4; ++qi) { e[qi] = __expf(m[qi] - mm) * l[qi]; se += e[qi]; }
    const float iL = 1.0f / se;
    #pragma unroll
    for (int qi = 0; qi < 4; ++qi) W[qi][t] = e[qi] * iL;
  }
  __syncthreads();

  // merge partials -> Y_lds (bf16)
  {
    const int r = t >> 3;
    #pragma unroll
    for (int seg = 0; seg < 4; ++seg) {
      const int c0 = (t & 7) * 8 + seg * 64;
      float acc[8] = {0.f, 0.f, 0.f, 0.f, 0.f, 0.f, 0.f, 0.f};
      #pragma unroll
      for (int qi = 0; qi < 4; ++qi) {
        h16x8 hv = *reinterpret_cast<const h16x8*>(
            Opart + ((p0 + qi) * 128 + rb + r) * 256 + c0);
        const float wq = W[qi][r];
        #pragma unroll
        for (int j = 0; j < 8; ++j) acc[j] += (float)hv[j] * wq;
      }
      u16x8 y;
      #pragma unroll
      for (int j = 0; j < 8; ++j) y[j] = f2bf(acc[j]);
      *reinterpret_cast<u16x8*>(&Y_lds[r][c0]) = y;
    }
  }
  __syncthreads();

  // projection + residual: wave w -> output rows o = w*32 .. w*32+31
  const int w    = t >> 6;
  const int lane = t & 63;
  const int q    = lane >> 4;
  const int mr   = lane & 15;
  #pragma unroll
  for (int ot = 0; ot < 2; ++ot) {
    const int o0 = w * 32 + ot * 16;
    bfrag a[8];
    {
      const bfrag* ap = reinterpret_cast<const bfrag*>(pwb + (o0 + mr) * CH);
      #pragma unroll
      for (int k = 0; k < 8; ++k) a[k] = ap[k * 4 + q];
    }
    #pragma unroll
    for (int st = 0; st < 4; ++st) {
      f32x4 acc = {0.f, 0.f, 0.f, 0.f};
      const bfrag* bp = reinterpret_cast<const bfrag*>(&Y_lds[st * 16 + mr][0]);
      #pragma unroll
      for (int k = 0; k < 8; ++k)
        acc = __builtin_amdgcn_mfma_f32_16x16x32_bf16(a[k], bp[k * 4 + q], acc, 0, 0, 0);
      #pragma unroll
      for (int i = 0; i < 4; ++i) {
        const int o = o0 + q * 4 + i;
        const int s = s0 + st * 16 + mr;
        const size_t idx = ((size_t)n * CH + o) * SS + s;
        out[idx] = x[idx] + acc[i];
      }
    }
  }
}

// ---------------------------------------------------------------------------
// Fallback (ws too small for partials): round-5 fused full-key kernel,
// verbatim (measured 113.6 us; total 195.8 us). Fits in 16.6 MB workspace.
// ---------------------------------------------------------------------------
__global__ __launch_bounds__(512, 2) void pass2_full(
    const unsigned short* __restrict__ Qt,
    const unsigned short* __restrict__ Kt,
    const unsigned short* __restrict__ xb,
    const unsigned short* __restrict__ pwb,
    const float* __restrict__ x,
    float* __restrict__ out)
{
  __shared__ __align__(16) unsigned char SMEM[51968];
  float          (*S_lds)[132] = reinterpret_cast<float(*)[132]>(SMEM);
  unsigned short (*P_lds)[136] = reinterpret_cast<unsigned short(*)[136]>(SMEM + 33792);
  float* row_m     = reinterpret_cast<float*>(SMEM + 51200);
  float* row_l     = reinterpret_cast<float*>(SMEM + 51456);
  float* row_alpha = reinterpret_cast<float*>(SMEM + 51712);

  const int t    = threadIdx.x;
  const int id   = blockIdx.x;
  const int xcd  = id & 7;
  const int n    = xcd >> 1;
  const int s0   = ((id >> 3) * 2 + (xcd & 1)) * 64;
  const int w    = t >> 6;
  const int lane = t & 63;
  const int q    = lane >> 4;
  const int mr   = lane & 15;

  if (t < 64) { row_m[t] = -INFINITY; row_l[t] = 0.f; }

  bfrag qa[4][4];
  #pragma unroll
  for (int ms = 0; ms < 4; ++ms) {
    const bfrag* rp = reinterpret_cast<const bfrag*>(
        Qt + ((size_t)n * SS + s0 + ms * 16 + mr) * EE);
    #pragma unroll
    for (int k = 0; k < 4; ++k) qa[ms][k] = rp[k * 4 + q];
  }

  f32x4 o_acc[4][2];
  #pragma unroll
  for (int ms = 0; ms < 4; ++ms)
    #pragma unroll
    for (int nt = 0; nt < 2; ++nt) o_acc[ms][nt] = (f32x4){0.f, 0.f, 0.f, 0.f};

  bfrag kb[4];
  {
    const bfrag* rp = reinterpret_cast<const bfrag*>(
        Kt + ((size_t)n * SS + w * 16 + mr) * EE);
    #pragma unroll
    for (int k = 0; k < 4; ++k) kb[k] = rp[k * 4 + q];
  }

  for (int t0 = 0; t0 < SS; t0 += 128) {
    bfrag vb[4][2];
    #pragma unroll
    for (int nt = 0; nt < 2; ++nt) {
      const int c = w * 32 + nt * 16 + mr;
      const bfrag* vp = reinterpret_cast<const bfrag*>(
          xb + ((size_t)n * CH + c) * SS + t0);
      #pragma unroll
      for (int kk = 0; kk < 4; ++kk) vb[kk][nt] = vp[kk * 4 + q];
    }

    #pragma unroll
    for (int ms = 0; ms < 4; ++ms) {
      f32x4 acc = {0.f, 0.f, 0.f, 0.f};
      #pragma unroll
      for (int k = 0; k < 4; ++k)
        acc = __builtin_amdgcn_mfma_f32_16x16x32_bf16(qa[ms][k], kb[k], acc, 0, 0, 0);
      #pragma unroll
      for (int i = 0; i < 4; ++i)
        S_lds[ms * 16 + q * 4 + i][w * 16 + mr] = acc[i];
    }
    lds_barrier();

    {
      const int t1 = t0 + 128;
      if (t1 < SS) {
        const bfrag* rp = reinterpret_cast<const bfrag*>(
            Kt + ((size_t)n * SS + t1 + w * 16 + mr) * EE);
        #pragma unroll
        for (int k = 0; k < 4; ++k) kb[k] = rp[k * 4 + q];
      }
    }

    {
      const int r  = t >> 3;
      const int cg = t & 7;
      const float4* srow = reinterpret_cast<const float4*>(&S_lds[r][cg * 16]);
      float4 v0 = srow[0], v1 = srow[1], v2 = srow[2], v3 = srow[3];
      float vmax = fmaxf(fmaxf(fmaxf(v0.x, v0.y), fmaxf(v0.z, v0.w)),
                         fmaxf(fmaxf(v1.x, v1.y), fmaxf(v1.z, v1.w)));
      vmax = fmaxf(vmax, fmaxf(fmaxf(fmaxf(v2.x, v2.y), fmaxf(v2.z, v2.w)),
                               fmaxf(fmaxf(v3.x, v3.y), fmaxf(v3.z, v3.w))));
      vmax = fmaxf(vmax, __shfl_xor(vmax, 1, 8));
      vmax = fmaxf(vmax, __shfl_xor(vmax, 2, 8));
      vmax = fmaxf(vmax, __shfl_xor(vmax, 4, 8));
      const float m_old = row_m[r];
      const float m_new = fmaxf(m_old, vmax);

      float p[16];
      p[0]=__expf(v0.x-m_new); p[1]=__expf(v0.y-m_new); p[2]=__expf(v0.z-m_new); p[3]=__expf(v0.w-m_new);
      p[4]=__expf(v1.x-m_new); p[5]=__expf(v1.y-m_new); p[6]=__expf(v1.z-m_new); p[7]=__expf(v1.w-m_new);
      p[8]=__expf(v2.x-m_new); p[9]=__expf(v2.y-m_new); p[10]=__expf(v2.z-m_new); p[11]=__expf(v2.w-m_new);
      p[12]=__expf(v3.x-m_new); p[13]=__expf(v3.y-m_new); p[14]=__expf(v3.z-m_new); p[15]=__expf(v3.w-m_new);
      float sum = 0.f;
      u16x8 pk0, pk1;
      #pragma unroll
      for (int j = 0; j < 8; ++j) { sum += p[j];     pk0[j] = f2bf(p[j]); }
      #pragma unroll
      for (int j = 0; j < 8; ++j) { sum += p[8 + j]; pk1[j] = f2bf(p[8 + j]); }
      *reinterpret_cast<u16x8*>(&P_lds[r][cg * 16])     = pk0;
      *reinterpret_cast<u16x8*>(&P_lds[r][cg * 16 + 8]) = pk1;
      sum += __shfl_xor(sum, 1, 8);
      sum += __shfl_xor(sum, 2, 8);
      sum += __shfl_xor(sum, 4, 8);
      if (cg == 0) {
        const float al = __expf(m_old - m_new);
        row_alpha[r] = al;
        row_m[r]     = m_new;
        row_l[r]     = row_l[r] * al + sum;
      }
    }
    lds_barrier();

    #pragma unroll
    for (int ms = 0; ms < 4; ++ms) {
      float al[4];
      #pragma unroll
      for (int i = 0; i < 4; ++i) al[i] = row_alpha[ms * 16 + q * 4 + i];
      #pragma unroll
      for (int nt = 0; nt < 2; ++nt)
        #pragma unroll
        for (int i = 0; i < 4; ++i) o_acc[ms][nt][i] *= al[i];
    }

    #pragma unroll
    for (int kk = 0; kk < 4; ++kk) {
      bfrag pa[4];
      #pragma unroll
      for (int ms = 0; ms < 4; ++ms)
        pa[ms] = reinterpret_cast<const bfrag*>(&P_lds[ms * 16 + mr][0])[kk * 4 + q];
      #pragma unroll
      for (int nt = 0; nt < 2; ++nt)
        #pragma unroll
        for (int ms = 0; ms < 4; ++ms)
          o_acc[ms][nt] = __builtin_amdgcn_mfma_f32_16x16x32_bf16(
              pa[ms], vb[kk][nt], o_acc[ms][nt], 0, 0, 0);
    }
  }

  __syncthreads();
  unsigned short (*Y_lds)[CH + 8] =
      reinterpret_cast<unsigned short(*)[CH + 8]>(SMEM);

  #pragma unroll
  for (int ms = 0; ms < 4; ++ms) {
    float inv[4];
    #pragma unroll
    for (int i = 0; i < 4; ++i) inv[i] = 1.0f / row_l[ms * 16 + q * 4 + i];
    #pragma unroll
    for (int nt = 0; nt < 2; ++nt) {
      const int c = w * 32 + nt * 16 + mr;
      #pragma unroll
      for (int i = 0; i < 4; ++i)
        Y_lds[ms * 16 + q * 4 + i][c] = f2bf(o_acc[ms][nt][i] * inv[i]);
    }
  }
  __syncthreads();

  #pragma unroll
  for (int ot = 0; ot < 2; ++ot) {
    const int o0 = w * 32 + ot * 16;
    bfrag a[8];
    {
      const bfrag* ap = reinterpret_cast<const bfrag*>(pwb + (o0 + mr) * CH);
      #pragma unroll
      for (int k = 0; k < 8; ++k) a[k] = ap[k * 4 + q];
    }
    #pragma unroll
    for (int st = 0; st < 4; ++st) {
      f32x4 acc = {0.f, 0.f, 0.f, 0.f};
      const bfrag* bp = reinterpret_cast<const bfrag*>(&Y_lds[st * 16 + mr][0]);
      #pragma unroll
      for (int k = 0; k < 8; ++k)
        acc = __builtin_amdgcn_mfma_f32_16x16x32_bf16(a[k], bp[k * 4 + q], acc, 0, 0, 0);
      #pragma unroll
      for (int i = 0; i < 4; ++i) {
        const int o = o0 + q * 4 + i;
        const int s = s0 + st * 16 + mr;
        const size_t idx = ((size_t)n * CH + o) * SS + s;
        out[idx] = x[idx] + acc[i];
      }
    }
  }
}

// ---------------------------------------------------------------------------
extern "C" void kernel_launch(void* const* d_in, const int* in_sizes, int n_in,
                              void* d_out, int out_size, void* d_ws, size_t ws_size,
                              hipStream_t stream) {
  const float* x   = (const float*)d_in[0];
  const float* thw = (const float*)d_in[1];
  const float* phw = (const float*)d_in[2];
  const float* pw  = (const float*)d_in[3];
  float* out = (float*)d_out;

  unsigned short* xb   = (unsigned short*)d_ws;               // 8 MB
  unsigned short* Qt   = xb + (size_t)NB * CH * SS;           // 4 MB
  unsigned short* Kt   = Qt + (size_t)NB * SS * EE;           // 4 MB
  unsigned short* thwb = Kt + (size_t)NB * SS * EE;           // 64 KB
  unsigned short* phwb = thwb + EE * CH;                      // 64 KB
  unsigned short* pwb  = phwb + EE * CH;                      // 128 KB
  float*          ML   = (float*)(pwb + CH * CH);             // 512 KB (512p x 256)
  _Float16*       Opart = (_Float16*)(ML + (size_t)512 * 256);

  // strict gating: Opart = 512 partials x 128 x 256 fp16 = 33.55 MB.
  const size_t opart_off  = (size_t)((char*)Opart - (char*)d_ws);
  const size_t opart_bytes = (size_t)512 * 128 * 256 * 2;
  const int fits = ws_size >= opart_off + opart_bytes;

  const int nw4 = EE * CH / 4;
  const int np4 = CH * CH / 4;
  const int totw4 = 2 * nw4 + np4;
  cvt_w<<<(totw4 + 255) / 256, 256, 0, stream>>>(thw, phw, pw, thwb, phwb, pwb);

  pass1_qk<<<dim3(SS / 64, NB), 512, 0, stream>>>(x, thwb, phwb, xb, Qt, Kt);

  if (fits) {
    pass2a<<<dim3(512), 256, 0, stream>>>(Qt, Kt, xb, Opart, ML);
    pass2b<<<dim3(256), 512, 0, stream>>>(Opart, ML, pwb, x, out);
  } else {
    pass2_full<<<dim3(NB * SS / 64), 512, 0, stream>>>(Qt, Kt, xb, pwb, x, out);
  }
}

// Round 13
// 180.126 us; speedup vs baseline: 2.3640x; 1.8347x over previous
//
#include <hip/hip_runtime.h>
#include <cstdint>
#include <cstddef>

#define NB 4
#define CH 256
#define SS 4096
#define EE 128
#define QSCALE 0.08838834764831845f /* 1/sqrt(128) */

typedef __attribute__((ext_vector_type(8))) short bfrag;          // 8 bf16 = 4 VGPR
typedef __attribute__((ext_vector_type(8))) unsigned short u16x8; // 16B ld/st
typedef __attribute__((ext_vector_type(8))) _Float16 h16x8;       // 16B fp16
typedef __attribute__((ext_vector_type(4))) float f32x4;          // MFMA acc

__device__ __forceinline__ unsigned short f2bf(float f) {
  union { float f; unsigned int u; } v; v.f = f;
  unsigned int u = v.u;
  unsigned int r = u + 0x7FFFu + ((u >> 16) & 1u);  // RNE
  return (unsigned short)(r >> 16);
}

// LDS-only barrier: waits DS ops, leaves global loads in flight.
__device__ __forceinline__ void lds_barrier() {
  asm volatile("s_waitcnt lgkmcnt(0)" ::: "memory");
  __builtin_amdgcn_s_barrier();
}

// XOR bank swizzle (T2/G4): power-of-2 row stride + byte^((row&7)<<4).
// Same involution on write and read sides -> correctness-neutral.
__device__ __forceinline__ unsigned char* swz(
    unsigned char* base, int row, int rowStrideBytes, int byteInRow) {
  return base + row * rowStrideBytes + (byteInRow ^ ((row & 7) << 4));
}

// ---------------------------------------------------------------------------
// Pass 0: weights-only fp32 -> bf16
// ---------------------------------------------------------------------------
__global__ __launch_bounds__(256) void cvt_w(
    const float* __restrict__ thw, const float* __restrict__ phw,
    const float* __restrict__ pw,
    unsigned short* __restrict__ thwb, unsigned short* __restrict__ phwb,
    unsigned short* __restrict__ pwb)
{
  const int nw4 = EE * CH / 4;   // 8192
  const int np4 = CH * CH / 4;   // 16384
  int i = blockIdx.x * 256 + threadIdx.x;
  const float* src; unsigned short* dst; int off;
  if      (i < nw4)           { src = thw; dst = thwb; off = i; }
  else if (i < 2 * nw4)       { src = phw; dst = phwb; off = i - nw4; }
  else if (i < 2 * nw4 + np4) { src = pw;  dst = pwb;  off = i - 2 * nw4; }
  else return;
  float4 v = reinterpret_cast<const float4*>(src)[off];
  ushort4 o;
  o.x = f2bf(v.x); o.y = f2bf(v.y); o.z = f2bf(v.z); o.w = f2bf(v.w);
  reinterpret_cast<ushort4*>(dst)[off] = o;
}

// ---------------------------------------------------------------------------
// Pass 1 (fused): x fp32->bf16 (xb byproduct) + theta/phi projections.
// ---------------------------------------------------------------------------
__global__ __launch_bounds__(512) void pass1_qk(
    const float* __restrict__ x,
    const unsigned short* __restrict__ thw,
    const unsigned short* __restrict__ phw,
    unsigned short* __restrict__ xb,
    unsigned short* __restrict__ Qt,
    unsigned short* __restrict__ Kt)
{
  __shared__ unsigned short xT[64][CH + 8];
  const int t  = threadIdx.x;
  const int n  = blockIdx.y;
  const int s0 = blockIdx.x * 64;

  {
    const int soff = (t & 15) * 4;
    const int c0   = t >> 4;           // 0..31
    #pragma unroll
    for (int ci = 0; ci < 8; ++ci) {
      const int c = c0 + ci * 32;
      const size_t rowoff = ((size_t)n * CH + c) * SS + s0;
      float4 v = reinterpret_cast<const float4*>(x + rowoff)[soff >> 2];
      ushort4 o;
      o.x = f2bf(v.x); o.y = f2bf(v.y); o.z = f2bf(v.z); o.w = f2bf(v.w);
      reinterpret_cast<ushort4*>(xb + rowoff)[soff >> 2] = o;
      xT[soff + 0][c] = o.x;
      xT[soff + 1][c] = o.y;
      xT[soff + 2][c] = o.z;
      xT[soff + 3][c] = o.w;
    }
  }
  __syncthreads();

  const int w    = t >> 6;        // 0..7
  const int lane = t & 63;
  const int q    = lane >> 4;
  const int mr   = lane & 15;
  const int wrow = (w & 3) * 16;
  const int half = w >> 2;        // 0: theta->Qt, 1: phi->Kt

  bfrag a[8];
  {
    const bfrag* rp = reinterpret_cast<const bfrag*>(&xT[wrow + mr][0]);
    #pragma unroll
    for (int k = 0; k < 8; ++k) a[k] = rp[k * 4 + q];
  }

  const unsigned short* wsel = half ? phw : thw;
  unsigned short*       osel = half ? Kt  : Qt;
  const float           sc   = half ? 1.0f : QSCALE;
  const bfrag* wp = reinterpret_cast<const bfrag*>(wsel);
  #pragma unroll
  for (int nt = 0; nt < 8; ++nt) {
    f32x4 acc = {0.f, 0.f, 0.f, 0.f};
    #pragma unroll
    for (int k = 0; k < 8; ++k) {
      bfrag b = wp[(nt * 16 + mr) * (CH / 8) + k * 4 + q];
      acc = __builtin_amdgcn_mfma_f32_16x16x32_bf16(a[k], b, acc, 0, 0, 0);
    }
    #pragma unroll
    for (int i = 0; i < 4; ++i) {
      const int srow = s0 + wrow + q * 4 + i;
      osel[((size_t)n * SS + srow) * EE + nt * 16 + mr] = f2bf(acc[i] * sc);
    }
  }
}

// ---------------------------------------------------------------------------
// Pass 2a (r13 = r12 resubmitted; bench never ran due to GPU acquisition
// timeout). r7's 94.5us structure + LDS XOR swizzle + fp16 partials.
// Q-tile 128, keys split 2-way (2048/block, 256 blocks, 512 thr, (512,2)).
// r7's measured SQ_LDS_BANK_CONFLICT = 9.4M cycles (~16%/CU): the 272B row
// strides put the 16-row x 4-chunk ds_read_b128 fragment reads (aq, pa) in
// 4-8-way conflict. Fix (verified T2/G4, m201): power-of-2 row strides
// (Q 256B, S 512B, P 256B) + byte ^ ((row&7)<<4) on writer AND reader.
// Partials fp16 (r8-verified numerics), halving pass2a WRITE + pass2b FETCH.
// ---------------------------------------------------------------------------
__global__ __launch_bounds__(512, 2) void pass2a(
    const unsigned short* __restrict__ Qt,
    const unsigned short* __restrict__ Kt,
    const unsigned short* __restrict__ xb,
    _Float16* __restrict__ Opart,
    float* __restrict__ ML)
{
  //   [0      .. 32768)   Q  u16 rows of 256B (swizzled)
  //   [32768  .. 98304)   S  f32 rows of 512B (swizzled)
  //   [98304  .. 131072)  P  u16 rows of 256B (swizzled)
  //   [131072 .. 132608)  row_m / row_l / row_alpha  f32[128] each
  __shared__ __align__(16) unsigned char SMEM[132608];
  unsigned char* Qb = SMEM;
  unsigned char* Sb = SMEM + 32768;
  unsigned char* Pb = SMEM + 98304;
  float* row_m     = reinterpret_cast<float*>(SMEM + 131072);
  float* row_l     = reinterpret_cast<float*>(SMEM + 131584);
  float* row_alpha = reinterpret_cast<float*>(SMEM + 132096);

  const int t     = threadIdx.x;
  const int id    = blockIdx.x;
  const int xcd   = id & 7;
  const int n     = xcd >> 1;        // image pinned to XCD pair
  const int h     = xcd & 1;         // key half
  const int qt    = id >> 3;         // 0..31
  const int s0    = qt * 128;
  const int kbase = h * 2048;

  const int w    = t >> 6;      // 0..7
  const int lane = t & 63;
  const int q    = lane >> 4;
  const int mr   = lane & 15;

  if (t < 128) { row_m[t] = -INFINITY; row_l[t] = 0.f; }

  // stage the 128-row Q tile (coalesced 16B chunks, swizzled dest)
  {
    const int col = (t & 15) * 16;       // byte within row
    #pragma unroll
    for (int j = 0; j < 4; ++j) {
      const int row = (t >> 4) + j * 32;
      *reinterpret_cast<u16x8*>(swz(Qb, row, 256, col)) =
          *reinterpret_cast<const u16x8*>(
              Qt + ((size_t)n * SS + s0 + row) * EE + (col >> 1));
    }
  }

  f32x4 o_accA[4][2], o_accB[4][2];
  #pragma unroll
  for (int ms = 0; ms < 4; ++ms)
    #pragma unroll
    for (int nt = 0; nt < 2; ++nt) {
      o_accA[ms][nt] = (f32x4){0.f, 0.f, 0.f, 0.f};
      o_accB[ms][nt] = (f32x4){0.f, 0.f, 0.f, 0.f};
    }

  __syncthreads();   // Q + row init visible

  // K fragments for iter 0: wave w -> key cols w*16..+15
  bfrag kb[4];
  {
    const bfrag* rp = reinterpret_cast<const bfrag*>(
        Kt + ((size_t)n * SS + kbase + w * 16 + mr) * EE);
    #pragma unroll
    for (int k = 0; k < 4; ++k) kb[k] = rp[k * 4 + q];
  }

#define QK_HALF(RB)                                                          \
  do {                                                                       \
    _Pragma("unroll")                                                        \
    for (int ms = 0; ms < 4; ++ms) {                                         \
      f32x4 acc = {0.f, 0.f, 0.f, 0.f};                                      \
      _Pragma("unroll")                                                      \
      for (int k = 0; k < 4; ++k) {                                          \
        bfrag aq = *reinterpret_cast<const bfrag*>(                          \
            swz(Qb, (RB) + ms * 16 + mr, 256, (k * 4 + q) * 16));            \
        acc = __builtin_amdgcn_mfma_f32_16x16x32_bf16(aq, kb[k], acc, 0,0,0);\
      }                                                                      \
      _Pragma("unroll")                                                      \
      for (int i = 0; i < 4; ++i)                                            \
        *reinterpret_cast<float*>(                                           \
            swz(Sb, (RB) + ms * 16 + q * 4 + i, 512, (w * 16 + mr) * 4)) =   \
            acc[i];                                                          \
    }                                                                        \
  } while (0)

#define PV_HALF(OACC, RB)                                                    \
  do {                                                                       \
    _Pragma("unroll")                                                        \
    for (int ms = 0; ms < 4; ++ms) {                                         \
      float al[4];                                                           \
      _Pragma("unroll")                                                      \
      for (int i = 0; i < 4; ++i) al[i] = row_alpha[(RB) + ms*16 + q*4 + i]; \
      _Pragma("unroll")                                                      \
      for (int nt = 0; nt < 2; ++nt)                                         \
        _Pragma("unroll")                                                    \
        for (int i = 0; i < 4; ++i) OACC[ms][nt][i] *= al[i];                \
    }                                                                        \
    _Pragma("unroll")                                                        \
    for (int kk = 0; kk < 4; ++kk) {                                         \
      bfrag pa[4];                                                           \
      _Pragma("unroll")                                                      \
      for (int ms = 0; ms < 4; ++ms)                                         \
        pa[ms] = *reinterpret_cast<const bfrag*>(                            \
            swz(Pb, (RB) + ms * 16 + mr, 256, (kk * 4 + q) * 16));           \
      _Pragma("unroll")                                                      \
      for (int nt = 0; nt < 2; ++nt)                                         \
        _Pragma("unroll")                                                    \
        for (int ms = 0; ms < 4; ++ms)                                       \
          OACC[ms][nt] = __builtin_amdgcn_mfma_f32_16x16x32_bf16(            \
              pa[ms], vb[kk][nt], OACC[ms][nt], 0, 0, 0);                    \
    }                                                                        \
  } while (0)

  for (int t0 = 0; t0 < 2048; t0 += 128) {
    // ---- V fragments for THIS iter (in flight across barriers) ----
    bfrag vb[4][2];
    #pragma unroll
    for (int nt = 0; nt < 2; ++nt) {
      const int c = w * 32 + nt * 16 + mr;
      const bfrag* vp = reinterpret_cast<const bfrag*>(
          xb + ((size_t)n * CH + c) * SS + kbase + t0);
      #pragma unroll
      for (int kk = 0; kk < 4; ++kk) vb[kk][nt] = vp[kk * 4 + q];
    }

    // ---- QK^T for both 64-row halves (kb reused) ----
    QK_HALF(0);
    QK_HALF(64);
    lds_barrier();

    // ---- prefetch K fragments for NEXT iter ----
    if (t0 + 128 < 2048) {
      const bfrag* rp = reinterpret_cast<const bfrag*>(
          Kt + ((size_t)n * SS + kbase + t0 + 128 + w * 16 + mr) * EE);
      #pragma unroll
      for (int k = 0; k < 4; ++k) kb[k] = rp[k * 4 + q];
    }

    // ---- online softmax: 8 lanes/row, rows 0..63 then 64..127 ----
    #pragma unroll
    for (int sh = 0; sh < 2; ++sh) {
      const int r  = sh * 64 + (t >> 3);
      const int cg = t & 7;
      float4 v0 = *reinterpret_cast<const float4*>(swz(Sb, r, 512, cg * 64));
      float4 v1 = *reinterpret_cast<const float4*>(swz(Sb, r, 512, cg * 64 + 16));
      float4 v2 = *reinterpret_cast<const float4*>(swz(Sb, r, 512, cg * 64 + 32));
      float4 v3 = *reinterpret_cast<const float4*>(swz(Sb, r, 512, cg * 64 + 48));
      float vmax = fmaxf(fmaxf(fmaxf(v0.x, v0.y), fmaxf(v0.z, v0.w)),
                         fmaxf(fmaxf(v1.x, v1.y), fmaxf(v1.z, v1.w)));
      vmax = fmaxf(vmax, fmaxf(fmaxf(fmaxf(v2.x, v2.y), fmaxf(v2.z, v2.w)),
                               fmaxf(fmaxf(v3.x, v3.y), fmaxf(v3.z, v3.w))));
      vmax = fmaxf(vmax, __shfl_xor(vmax, 1, 8));
      vmax = fmaxf(vmax, __shfl_xor(vmax, 2, 8));
      vmax = fmaxf(vmax, __shfl_xor(vmax, 4, 8));
      const float m_old = row_m[r];
      const float m_new = fmaxf(m_old, vmax);

      float p[16];
      p[0]=__expf(v0.x-m_new); p[1]=__expf(v0.y-m_new); p[2]=__expf(v0.z-m_new); p[3]=__expf(v0.w-m_new);
      p[4]=__expf(v1.x-m_new); p[5]=__expf(v1.y-m_new); p[6]=__expf(v1.z-m_new); p[7]=__expf(v1.w-m_new);
      p[8]=__expf(v2.x-m_new); p[9]=__expf(v2.y-m_new); p[10]=__expf(v2.z-m_new); p[11]=__expf(v2.w-m_new);
      p[12]=__expf(v3.x-m_new); p[13]=__expf(v3.y-m_new); p[14]=__expf(v3.z-m_new); p[15]=__expf(v3.w-m_new);
      float sum = 0.f;
      u16x8 pk0, pk1;
      #pragma unroll
      for (int j = 0; j < 8; ++j) { sum += p[j];     pk0[j] = f2bf(p[j]); }
      #pragma unroll
      for (int j = 0; j < 8; ++j) { sum += p[8 + j]; pk1[j] = f2bf(p[8 + j]); }
      *reinterpret_cast<u16x8*>(swz(Pb, r, 256, cg * 32))      = pk0;
      *reinterpret_cast<u16x8*>(swz(Pb, r, 256, cg * 32 + 16)) = pk1;
      sum += __shfl_xor(sum, 1, 8);
      sum += __shfl_xor(sum, 2, 8);
      sum += __shfl_xor(sum, 4, 8);
      if (cg == 0) {
        const float al = __expf(m_old - m_new);   // exp(-inf)=0 on iter 0
        row_alpha[r] = al;
        row_m[r]     = m_new;
        row_l[r]     = row_l[r] * al + sum;
      }
    }
    lds_barrier();

    // ---- rescale + PV for both halves (vb reused) ----
    PV_HALF(o_accA, 0);
    PV_HALF(o_accB, 64);
  }

  // ---- epilogue: normalized fp16 partials + (m,l) ----
  const size_t p = ((size_t)(n * 32 + qt)) * 2 + h;

#define EPI_HALF(OACC, RB)                                                   \
  do {                                                                       \
    _Pragma("unroll")                                                        \
    for (int ms = 0; ms < 4; ++ms) {                                         \
      float inv[4];                                                          \
      _Pragma("unroll")                                                      \
      for (int i = 0; i < 4; ++i)                                            \
        inv[i] = 1.0f / row_l[(RB) + ms * 16 + q * 4 + i];                   \
      _Pragma("unroll")                                                      \
      for (int nt = 0; nt < 2; ++nt)                                         \
        _Pragma("unroll")                                                    \
        for (int i = 0; i < 4; ++i) {                                        \
          const size_t oi =                                                  \
              (p * 128 + (RB) + ms * 16 + q * 4 + i) * 256 +                 \
              w * 32 + nt * 16 + mr;                                         \
          Opart[oi] = (_Float16)(OACC[ms][nt][i] * inv[i]);                  \
        }                                                                    \
    }                                                                        \
  } while (0)

  EPI_HALF(o_accA, 0);
  EPI_HALF(o_accB, 64);
  if (t < 128) {
    ML[p * 256 + t * 2]     = row_m[t];
    ML[p * 256 + t * 2 + 1] = row_l[t];
  }
}

// ---------------------------------------------------------------------------
// Pass 2b: merge the two key-halves + projection + residual (r8-verified).
// ---------------------------------------------------------------------------
__global__ __launch_bounds__(512) void pass2b(
    const _Float16* __restrict__ Opart,
    const float* __restrict__ ML,
    const unsigned short* __restrict__ pwb,
    const float* __restrict__ x,
    float* __restrict__ out)
{
  __shared__ __align__(16) unsigned char SMEM[34816];
  unsigned short (*Y_lds)[CH + 8] =
      reinterpret_cast<unsigned short(*)[CH + 8]>(SMEM);   // 64*264*2 = 33792
  float* w0 = reinterpret_cast<float*>(SMEM + 33792);      // 64 f32
  float* w1 = reinterpret_cast<float*>(SMEM + 34048);      // 64 f32

  const int t   = threadIdx.x;
  const int id  = blockIdx.x;
  const int n   = id >> 6;
  const int sub = id & 63;
  const int s0  = sub * 64;
  const int qt  = sub >> 1;
  const int rb  = (sub & 1) * 64;          // row range within the q-tile
  const size_t p0 = ((size_t)(n * 32 + qt)) * 2;

  if (t < 64) {
    const float ma = ML[p0 * 256 + (rb + t) * 2];
    const float la = ML[p0 * 256 + (rb + t) * 2 + 1];
    const float mb = ML[(p0 + 1) * 256 + (rb + t) * 2];
    const float lb = ML[(p0 + 1) * 256 + (rb + t) * 2 + 1];
    const float m  = fmaxf(ma, mb);
    const float e0 = __expf(ma - m) * la;
    const float e1 = __expf(mb - m) * lb;
    const float iL = 1.0f / (e0 + e1);
    w0[t] = e0 * iL;
    w1[t] = e1 * iL;
  }
  __syncthreads();

  // merge partials -> Y_lds (bf16)
  {
    const int r = t >> 3;
    #pragma unroll
    for (int seg = 0; seg < 4; ++seg) {
      const int c0 = (t & 7) * 8 + seg * 64;
      const size_t ai = (p0 * 128 + rb + r) * 256 + c0;
      const size_t bi = ((p0 + 1) * 128 + rb + r) * 256 + c0;
      h16x8 ha = *reinterpret_cast<const h16x8*>(Opart + ai);
      h16x8 hb = *reinterpret_cast<const h16x8*>(Opart + bi);
      u16x8 y;
      #pragma unroll
      for (int j = 0; j < 8; ++j)
        y[j] = f2bf((float)ha[j] * w0[r] + (float)hb[j] * w1[r]);
      *reinterpret_cast<u16x8*>(&Y_lds[r][c0]) = y;
    }
  }
  __syncthreads();

  // projection + residual: wave w -> output rows o = w*32 .. w*32+31
  const int w    = t >> 6;
  const int lane = t & 63;
  const int q    = lane >> 4;
  const int mr   = lane & 15;
  #pragma unroll
  for (int ot = 0; ot < 2; ++ot) {
    const int o0 = w * 32 + ot * 16;
    bfrag a[8];
    {
      const bfrag* ap = reinterpret_cast<const bfrag*>(pwb + (o0 + mr) * CH);
      #pragma unroll
      for (int k = 0; k < 8; ++k) a[k] = ap[k * 4 + q];
    }
    #pragma unroll
    for (int st = 0; st < 4; ++st) {
      f32x4 acc = {0.f, 0.f, 0.f, 0.f};
      const bfrag* bp = reinterpret_cast<const bfrag*>(&Y_lds[st * 16 + mr][0]);
      #pragma unroll
      for (int k = 0; k < 8; ++k)
        acc = __builtin_amdgcn_mfma_f32_16x16x32_bf16(a[k], bp[k * 4 + q], acc, 0, 0, 0);
      #pragma unroll
      for (int i = 0; i < 4; ++i) {
        const int o = o0 + q * 4 + i;
        const int s = s0 + st * 16 + mr;
        const size_t idx = ((size_t)n * CH + o) * SS + s;
        out[idx] = x[idx] + acc[i];
      }
    }
  }
}

// ---------------------------------------------------------------------------
// Fallback (ws too small for partials): round-5 fused full-key kernel,
// verbatim (measured 113.6 us; total 195.8 us). Fits in 16.6 MB workspace.
// ---------------------------------------------------------------------------
__global__ __launch_bounds__(512, 2) void pass2_full(
    const unsigned short* __restrict__ Qt,
    const unsigned short* __restrict__ Kt,
    const unsigned short* __restrict__ xb,
    const unsigned short* __restrict__ pwb,
    const float* __restrict__ x,
    float* __restrict__ out)
{
  __shared__ __align__(16) unsigned char SMEM[51968];
  float          (*S_lds)[132] = reinterpret_cast<float(*)[132]>(SMEM);
  unsigned short (*P_lds)[136] = reinterpret_cast<unsigned short(*)[136]>(SMEM + 33792);
  float* row_m     = reinterpret_cast<float*>(SMEM + 51200);
  float* row_l     = reinterpret_cast<float*>(SMEM + 51456);
  float* row_alpha = reinterpret_cast<float*>(SMEM + 51712);

  const int t    = threadIdx.x;
  const int id   = blockIdx.x;
  const int xcd  = id & 7;
  const int n    = xcd >> 1;
  const int s0   = ((id >> 3) * 2 + (xcd & 1)) * 64;
  const int w    = t >> 6;
  const int lane = t & 63;
  const int q    = lane >> 4;
  const int mr   = lane & 15;

  if (t < 64) { row_m[t] = -INFINITY; row_l[t] = 0.f; }

  bfrag qa[4][4];
  #pragma unroll
  for (int ms = 0; ms < 4; ++ms) {
    const bfrag* rp = reinterpret_cast<const bfrag*>(
        Qt + ((size_t)n * SS + s0 + ms * 16 + mr) * EE);
    #pragma unroll
    for (int k = 0; k < 4; ++k) qa[ms][k] = rp[k * 4 + q];
  }

  f32x4 o_acc[4][2];
  #pragma unroll
  for (int ms = 0; ms < 4; ++ms)
    #pragma unroll
    for (int nt = 0; nt < 2; ++nt) o_acc[ms][nt] = (f32x4){0.f, 0.f, 0.f, 0.f};

  bfrag kb[4];
  {
    const bfrag* rp = reinterpret_cast<const bfrag*>(
        Kt + ((size_t)n * SS + w * 16 + mr) * EE);
    #pragma unroll
    for (int k = 0; k < 4; ++k) kb[k] = rp[k * 4 + q];
  }

  for (int t0 = 0; t0 < SS; t0 += 128) {
    bfrag vb[4][2];
    #pragma unroll
    for (int nt = 0; nt < 2; ++nt) {
      const int c = w * 32 + nt * 16 + mr;
      const bfrag* vp = reinterpret_cast<const bfrag*>(
          xb + ((size_t)n * CH + c) * SS + t0);
      #pragma unroll
      for (int kk = 0; kk < 4; ++kk) vb[kk][nt] = vp[kk * 4 + q];
    }

    #pragma unroll
    for (int ms = 0; ms < 4; ++ms) {
      f32x4 acc = {0.f, 0.f, 0.f, 0.f};
      #pragma unroll
      for (int k = 0; k < 4; ++k)
        acc = __builtin_amdgcn_mfma_f32_16x16x32_bf16(qa[ms][k], kb[k], acc, 0, 0, 0);
      #pragma unroll
      for (int i = 0; i < 4; ++i)
        S_lds[ms * 16 + q * 4 + i][w * 16 + mr] = acc[i];
    }
    lds_barrier();

    {
      const int t1 = t0 + 128;
      if (t1 < SS) {
        const bfrag* rp = reinterpret_cast<const bfrag*>(
            Kt + ((size_t)n * SS + t1 + w * 16 + mr) * EE);
        #pragma unroll
        for (int k = 0; k < 4; ++k) kb[k] = rp[k * 4 + q];
      }
    }

    {
      const int r  = t >> 3;
      const int cg = t & 7;
      const float4* srow = reinterpret_cast<const float4*>(&S_lds[r][cg * 16]);
      float4 v0 = srow[0], v1 = srow[1], v2 = srow[2], v3 = srow[3];
      float vmax = fmaxf(fmaxf(fmaxf(v0.x, v0.y), fmaxf(v0.z, v0.w)),
                         fmaxf(fmaxf(v1.x, v1.y), fmaxf(v1.z, v1.w)));
      vmax = fmaxf(vmax, fmaxf(fmaxf(fmaxf(v2.x, v2.y), fmaxf(v2.z, v2.w)),
                               fmaxf(fmaxf(v3.x, v3.y), fmaxf(v3.z, v3.w))));
      vmax = fmaxf(vmax, __shfl_xor(vmax, 1, 8));
      vmax = fmaxf(vmax, __shfl_xor(vmax, 2, 8));
      vmax = fmaxf(vmax, __shfl_xor(vmax, 4, 8));
      const float m_old = row_m[r];
      const float m_new = fmaxf(m_old, vmax);

      float p[16];
      p[0]=__expf(v0.x-m_new); p[1]=__expf(v0.y-m_new); p[2]=__expf(v0.z-m_new); p[3]=__expf(v0.w-m_new);
      p[4]=__expf(v1.x-m_new); p[5]=__expf(v1.y-m_new); p[6]=__expf(v1.z-m_new); p[7]=__expf(v1.w-m_new);
      p[8]=__expf(v2.x-m_new); p[9]=__expf(v2.y-m_new); p[10]=__expf(v2.z-m_new); p[11]=__expf(v2.w-m_new);
      p[12]=__expf(v3.x-m_new); p[13]=__expf(v3.y-m_new); p[14]=__expf(v3.z-m_new); p[15]=__expf(v3.w-m_new);
      float sum = 0.f;
      u16x8 pk0, pk1;
      #pragma unroll
      for (int j = 0; j < 8; ++j) { sum += p[j];     pk0[j] = f2bf(p[j]); }
      #pragma unroll
      for (int j = 0; j < 8; ++j) { sum += p[8 + j]; pk1[j] = f2bf(p[8 + j]); }
      *reinterpret_cast<u16x8*>(&P_lds[r][cg * 16])     = pk0;
      *reinterpret_cast<u16x8*>(&P_lds[r][cg * 16 + 8]) = pk1;
      sum += __shfl_xor(sum, 1, 8);
      sum += __shfl_xor(sum, 2, 8);
      sum += __shfl_xor(sum, 4, 8);
      if (cg == 0) {
        const float al = __expf(m_old - m_new);
        row_alpha[r] = al;
        row_m[r]     = m_new;
        row_l[r]     = row_l[r] * al + sum;
      }
    }
    lds_barrier();

    #pragma unroll
    for (int ms = 0; ms < 4; ++ms) {
      float al[4];
      #pragma unroll
      for (int i = 0; i < 4; ++i) al[i] = row_alpha[ms * 16 + q * 4 + i];
      #pragma unroll
      for (int nt = 0; nt < 2; ++nt)
        #pragma unroll
        for (int i = 0; i < 4; ++i) o_acc[ms][nt][i] *= al[i];
    }

    #pragma unroll
    for (int kk = 0; kk < 4; ++kk) {
      bfrag pa[4];
      #pragma unroll
      for (int ms = 0; ms < 4; ++ms)
        pa[ms] = reinterpret_cast<const bfrag*>(&P_lds[ms * 16 + mr][0])[kk * 4 + q];
      #pragma unroll
      for (int nt = 0; nt < 2; ++nt)
        #pragma unroll
        for (int ms = 0; ms < 4; ++ms)
          o_acc[ms][nt] = __builtin_amdgcn_mfma_f32_16x16x32_bf16(
              pa[ms], vb[kk][nt], o_acc[ms][nt], 0, 0, 0);
    }
  }

  __syncthreads();
  unsigned short (*Y_lds)[CH + 8] =
      reinterpret_cast<unsigned short(*)[CH + 8]>(SMEM);

  #pragma unroll
  for (int ms = 0; ms < 4; ++ms) {
    float inv[4];
    #pragma unroll
    for (int i = 0; i < 4; ++i) inv[i] = 1.0f / row_l[ms * 16 + q * 4 + i];
    #pragma unroll
    for (int nt = 0; nt < 2; ++nt) {
      const int c = w * 32 + nt * 16 + mr;
      #pragma unroll
      for (int i = 0; i < 4; ++i)
        Y_lds[ms * 16 + q * 4 + i][c] = f2bf(o_acc[ms][nt][i] * inv[i]);
    }
  }
  __syncthreads();

  #pragma unroll
  for (int ot = 0; ot < 2; ++ot) {
    const int o0 = w * 32 + ot * 16;
    bfrag a[8];
    {
      const bfrag* ap = reinterpret_cast<const bfrag*>(pwb + (o0 + mr) * CH);
      #pragma unroll
      for (int k = 0; k < 8; ++k) a[k] = ap[k * 4 + q];
    }
    #pragma unroll
    for (int st = 0; st < 4; ++st) {
      f32x4 acc = {0.f, 0.f, 0.f, 0.f};
      const bfrag* bp = reinterpret_cast<const bfrag*>(&Y_lds[st * 16 + mr][0]);
      #pragma unroll
      for (int k = 0; k < 8; ++k)
        acc = __builtin_amdgcn_mfma_f32_16x16x32_bf16(a[k], bp[k * 4 + q], acc, 0, 0, 0);
      #pragma unroll
      for (int i = 0; i < 4; ++i) {
        const int o = o0 + q * 4 + i;
        const int s = s0 + st * 16 + mr;
        const size_t idx = ((size_t)n * CH + o) * SS + s;
        out[idx] = x[idx] + acc[i];
      }
    }
  }
}

// ---------------------------------------------------------------------------
extern "C" void kernel_launch(void* const* d_in, const int* in_sizes, int n_in,
                              void* d_out, int out_size, void* d_ws, size_t ws_size,
                              hipStream_t stream) {
  const float* x   = (const float*)d_in[0];
  const float* thw = (const float*)d_in[1];
  const float* phw = (const float*)d_in[2];
  const float* pw  = (const float*)d_in[3];
  float* out = (float*)d_out;

  unsigned short* xb   = (unsigned short*)d_ws;               // 8 MB
  unsigned short* Qt   = xb + (size_t)NB * CH * SS;           // 4 MB
  unsigned short* Kt   = Qt + (size_t)NB * SS * EE;           // 4 MB
  unsigned short* thwb = Kt + (size_t)NB * SS * EE;           // 64 KB
  unsigned short* phwb = thwb + EE * CH;                      // 64 KB
  unsigned short* pwb  = phwb + EE * CH;                      // 128 KB
  float*          ML   = (float*)(pwb + CH * CH);             // 256 KB
  _Float16*       Opart = (_Float16*)(ML + (size_t)256 * 128 * 2);

  // strict workspace gating (every Opart/ML byte covered)
  const size_t opart_off = (size_t)((char*)Opart - (char*)d_ws);
  const size_t opart_bytes = (size_t)256 * 128 * 256 * 2;     // 16.8 MB fp16
  const int fits = ws_size >= opart_off + opart_bytes;

  const int nw4 = EE * CH / 4;
  const int np4 = CH * CH / 4;
  const int totw4 = 2 * nw4 + np4;
  cvt_w<<<(totw4 + 255) / 256, 256, 0, stream>>>(thw, phw, pw, thwb, phwb, pwb);

  pass1_qk<<<dim3(SS / 64, NB), 512, 0, stream>>>(x, thwb, phwb, xb, Qt, Kt);

  if (fits) {
    pass2a<<<dim3(256), 512, 0, stream>>>(Qt, Kt, xb, Opart, ML);
    pass2b<<<dim3(256), 512, 0, stream>>>(Opart, ML, pwb, x, out);
  } else {
    pass2_full<<<dim3(NB * SS / 64), 512, 0, stream>>>(Qt, Kt, xb, pwb, x, out);
  }
}

// Round 14
// 179.004 us; speedup vs baseline: 2.3788x; 1.0063x over previous
//
#include <hip/hip_runtime.h>
#include <cstdint>
#include <cstddef>

#define NB 4
#define CH 256
#define SS 4096
#define EE 128
#define QSCALE 0.08838834764831845f /* 1/sqrt(128) */

typedef __attribute__((ext_vector_type(8))) short bfrag;          // 8 bf16 = 4 VGPR
typedef __attribute__((ext_vector_type(8))) unsigned short u16x8; // 16B ld/st
typedef __attribute__((ext_vector_type(4))) unsigned short u16x4; // 8B st
typedef __attribute__((ext_vector_type(8))) _Float16 h16x8;       // 16B fp16
typedef __attribute__((ext_vector_type(4))) float f32x4;          // MFMA acc

__device__ __forceinline__ unsigned short f2bf(float f) {
  union { float f; unsigned int u; } v; v.f = f;
  unsigned int u = v.u;
  unsigned int r = u + 0x7FFFu + ((u >> 16) & 1u);  // RNE
  return (unsigned short)(r >> 16);
}

// LDS-only barrier: waits DS ops, leaves global loads in flight.
__device__ __forceinline__ void lds_barrier() {
  asm volatile("s_waitcnt lgkmcnt(0)" ::: "memory");
  __builtin_amdgcn_s_barrier();
}

// XOR bank swizzle (T2/G4): power-of-2 row stride + byte^((row&7)<<4).
// Same involution on write and read sides -> correctness-neutral.
__device__ __forceinline__ unsigned char* swz(
    unsigned char* base, int row, int rowStrideBytes, int byteInRow) {
  return base + row * rowStrideBytes + (byteInRow ^ ((row & 7) << 4));
}

// ---------------------------------------------------------------------------
// Pass 0: weights-only fp32 -> bf16
// ---------------------------------------------------------------------------
__global__ __launch_bounds__(256) void cvt_w(
    const float* __restrict__ thw, const float* __restrict__ phw,
    const float* __restrict__ pw,
    unsigned short* __restrict__ thwb, unsigned short* __restrict__ phwb,
    unsigned short* __restrict__ pwb)
{
  const int nw4 = EE * CH / 4;   // 8192
  const int np4 = CH * CH / 4;   // 16384
  int i = blockIdx.x * 256 + threadIdx.x;
  const float* src; unsigned short* dst; int off;
  if      (i < nw4)           { src = thw; dst = thwb; off = i; }
  else if (i < 2 * nw4)       { src = phw; dst = phwb; off = i - nw4; }
  else if (i < 2 * nw4 + np4) { src = pw;  dst = pwb;  off = i - 2 * nw4; }
  else return;
  float4 v = reinterpret_cast<const float4*>(src)[off];
  ushort4 o;
  o.x = f2bf(v.x); o.y = f2bf(v.y); o.z = f2bf(v.z); o.w = f2bf(v.w);
  reinterpret_cast<ushort4*>(dst)[off] = o;
}

// ---------------------------------------------------------------------------
// Pass 1 (fused): x fp32->bf16 (xb byproduct) + theta/phi projections.
// ---------------------------------------------------------------------------
__global__ __launch_bounds__(512) void pass1_qk(
    const float* __restrict__ x,
    const unsigned short* __restrict__ thw,
    const unsigned short* __restrict__ phw,
    unsigned short* __restrict__ xb,
    unsigned short* __restrict__ Qt,
    unsigned short* __restrict__ Kt)
{
  __shared__ unsigned short xT[64][CH + 8];
  const int t  = threadIdx.x;
  const int n  = blockIdx.y;
  const int s0 = blockIdx.x * 64;

  {
    const int soff = (t & 15) * 4;
    const int c0   = t >> 4;           // 0..31
    #pragma unroll
    for (int ci = 0; ci < 8; ++ci) {
      const int c = c0 + ci * 32;
      const size_t rowoff = ((size_t)n * CH + c) * SS + s0;
      float4 v = reinterpret_cast<const float4*>(x + rowoff)[soff >> 2];
      ushort4 o;
      o.x = f2bf(v.x); o.y = f2bf(v.y); o.z = f2bf(v.z); o.w = f2bf(v.w);
      reinterpret_cast<ushort4*>(xb + rowoff)[soff >> 2] = o;
      xT[soff + 0][c] = o.x;
      xT[soff + 1][c] = o.y;
      xT[soff + 2][c] = o.z;
      xT[soff + 3][c] = o.w;
    }
  }
  __syncthreads();

  const int w    = t >> 6;        // 0..7
  const int lane = t & 63;
  const int q    = lane >> 4;
  const int mr   = lane & 15;
  const int wrow = (w & 3) * 16;
  const int half = w >> 2;        // 0: theta->Qt, 1: phi->Kt

  bfrag a[8];
  {
    const bfrag* rp = reinterpret_cast<const bfrag*>(&xT[wrow + mr][0]);
    #pragma unroll
    for (int k = 0; k < 8; ++k) a[k] = rp[k * 4 + q];
  }

  const unsigned short* wsel = half ? phw : thw;
  unsigned short*       osel = half ? Kt  : Qt;
  const float           sc   = half ? 1.0f : QSCALE;
  const bfrag* wp = reinterpret_cast<const bfrag*>(wsel);
  #pragma unroll
  for (int nt = 0; nt < 8; ++nt) {
    f32x4 acc = {0.f, 0.f, 0.f, 0.f};
    #pragma unroll
    for (int k = 0; k < 8; ++k) {
      bfrag b = wp[(nt * 16 + mr) * (CH / 8) + k * 4 + q];
      acc = __builtin_amdgcn_mfma_f32_16x16x32_bf16(a[k], b, acc, 0, 0, 0);
    }
    #pragma unroll
    for (int i = 0; i < 4; ++i) {
      const int srow = s0 + wrow + q * 4 + i;
      osel[((size_t)n * SS + srow) * EE + nt * 16 + mr] = f2bf(acc[i] * sc);
    }
  }
}

// ---------------------------------------------------------------------------
// Pass 2a (r14 = r13 + chunk-strided softmax S-reads).
// r13 post-mortem: SQ_LDS_BANK_CONFLICT bit-identical to r7 (9,437,184) --
// the conflicts were never in the fragment reads (272B stride was already
// 2-way-free); they are in the softmax S-read: 8 lanes/row at byte cg*64 ->
// dword bank (cg*16)%32 in {0,16} -> 4 lanes/bank on every chunk, invariant
// under the row-XOR (which shifts all lanes of a row together).
// Fix: lane cg reads chunk c at byte c*128 + cg*16; with the row-XOR the 8
// lanes of a row cover banks ((cg^d)*4..+3) = all 32 banks exactly once.
// Lane now owns cols {c*32+cg*4..+3} (max/sum commutative); P values land at
// their CANONICAL byte positions via 4x8B stores -> PV read side unchanged.
// ---------------------------------------------------------------------------
__global__ __launch_bounds__(512, 2) void pass2a(
    const unsigned short* __restrict__ Qt,
    const unsigned short* __restrict__ Kt,
    const unsigned short* __restrict__ xb,
    _Float16* __restrict__ Opart,
    float* __restrict__ ML)
{
  //   [0      .. 32768)   Q  u16 rows of 256B (swizzled)
  //   [32768  .. 98304)   S  f32 rows of 512B (swizzled)
  //   [98304  .. 131072)  P  u16 rows of 256B (swizzled)
  //   [131072 .. 132608)  row_m / row_l / row_alpha  f32[128] each
  __shared__ __align__(16) unsigned char SMEM[132608];
  unsigned char* Qb = SMEM;
  unsigned char* Sb = SMEM + 32768;
  unsigned char* Pb = SMEM + 98304;
  float* row_m     = reinterpret_cast<float*>(SMEM + 131072);
  float* row_l     = reinterpret_cast<float*>(SMEM + 131584);
  float* row_alpha = reinterpret_cast<float*>(SMEM + 132096);

  const int t     = threadIdx.x;
  const int id    = blockIdx.x;
  const int xcd   = id & 7;
  const int n     = xcd >> 1;        // image pinned to XCD pair
  const int h     = xcd & 1;         // key half
  const int qt    = id >> 3;         // 0..31
  const int s0    = qt * 128;
  const int kbase = h * 2048;

  const int w    = t >> 6;      // 0..7
  const int lane = t & 63;
  const int q    = lane >> 4;
  const int mr   = lane & 15;

  if (t < 128) { row_m[t] = -INFINITY; row_l[t] = 0.f; }

  // stage the 128-row Q tile (coalesced 16B chunks, swizzled dest)
  {
    const int col = (t & 15) * 16;       // byte within row
    #pragma unroll
    for (int j = 0; j < 4; ++j) {
      const int row = (t >> 4) + j * 32;
      *reinterpret_cast<u16x8*>(swz(Qb, row, 256, col)) =
          *reinterpret_cast<const u16x8*>(
              Qt + ((size_t)n * SS + s0 + row) * EE + (col >> 1));
    }
  }

  f32x4 o_accA[4][2], o_accB[4][2];
  #pragma unroll
  for (int ms = 0; ms < 4; ++ms)
    #pragma unroll
    for (int nt = 0; nt < 2; ++nt) {
      o_accA[ms][nt] = (f32x4){0.f, 0.f, 0.f, 0.f};
      o_accB[ms][nt] = (f32x4){0.f, 0.f, 0.f, 0.f};
    }

  __syncthreads();   // Q + row init visible

  // K fragments for iter 0: wave w -> key cols w*16..+15
  bfrag kb[4];
  {
    const bfrag* rp = reinterpret_cast<const bfrag*>(
        Kt + ((size_t)n * SS + kbase + w * 16 + mr) * EE);
    #pragma unroll
    for (int k = 0; k < 4; ++k) kb[k] = rp[k * 4 + q];
  }

#define QK_HALF(RB)                                                          \
  do {                                                                       \
    _Pragma("unroll")                                                        \
    for (int ms = 0; ms < 4; ++ms) {                                         \
      f32x4 acc = {0.f, 0.f, 0.f, 0.f};                                      \
      _Pragma("unroll")                                                      \
      for (int k = 0; k < 4; ++k) {                                          \
        bfrag aq = *reinterpret_cast<const bfrag*>(                          \
            swz(Qb, (RB) + ms * 16 + mr, 256, (k * 4 + q) * 16));            \
        acc = __builtin_amdgcn_mfma_f32_16x16x32_bf16(aq, kb[k], acc, 0,0,0);\
      }                                                                      \
      _Pragma("unroll")                                                      \
      for (int i = 0; i < 4; ++i)                                            \
        *reinterpret_cast<float*>(                                           \
            swz(Sb, (RB) + ms * 16 + q * 4 + i, 512, (w * 16 + mr) * 4)) =   \
            acc[i];                                                          \
    }                                                                        \
  } while (0)

#define PV_HALF(OACC, RB)                                                    \
  do {                                                                       \
    _Pragma("unroll")                                                        \
    for (int ms = 0; ms < 4; ++ms) {                                         \
      float al[4];                                                           \
      _Pragma("unroll")                                                      \
      for (int i = 0; i < 4; ++i) al[i] = row_alpha[(RB) + ms*16 + q*4 + i]; \
      _Pragma("unroll")                                                      \
      for (int nt = 0; nt < 2; ++nt)                                         \
        _Pragma("unroll")                                                    \
        for (int i = 0; i < 4; ++i) OACC[ms][nt][i] *= al[i];                \
    }                                                                        \
    _Pragma("unroll")                                                        \
    for (int kk = 0; kk < 4; ++kk) {                                         \
      bfrag pa[4];                                                           \
      _Pragma("unroll")                                                      \
      for (int ms = 0; ms < 4; ++ms)                                         \
        pa[ms] = *reinterpret_cast<const bfrag*>(                            \
            swz(Pb, (RB) + ms * 16 + mr, 256, (kk * 4 + q) * 16));           \
      _Pragma("unroll")                                                      \
      for (int nt = 0; nt < 2; ++nt)                                         \
        _Pragma("unroll")                                                    \
        for (int ms = 0; ms < 4; ++ms)                                       \
          OACC[ms][nt] = __builtin_amdgcn_mfma_f32_16x16x32_bf16(            \
              pa[ms], vb[kk][nt], OACC[ms][nt], 0, 0, 0);                    \
    }                                                                        \
  } while (0)

  for (int t0 = 0; t0 < 2048; t0 += 128) {
    // ---- V fragments for THIS iter (in flight across barriers) ----
    bfrag vb[4][2];
    #pragma unroll
    for (int nt = 0; nt < 2; ++nt) {
      const int c = w * 32 + nt * 16 + mr;
      const bfrag* vp = reinterpret_cast<const bfrag*>(
          xb + ((size_t)n * CH + c) * SS + kbase + t0);
      #pragma unroll
      for (int kk = 0; kk < 4; ++kk) vb[kk][nt] = vp[kk * 4 + q];
    }

    // ---- QK^T for both 64-row halves (kb reused) ----
    QK_HALF(0);
    QK_HALF(64);
    lds_barrier();

    // ---- prefetch K fragments for NEXT iter ----
    if (t0 + 128 < 2048) {
      const bfrag* rp = reinterpret_cast<const bfrag*>(
          Kt + ((size_t)n * SS + kbase + t0 + 128 + w * 16 + mr) * EE);
      #pragma unroll
      for (int k = 0; k < 4; ++k) kb[k] = rp[k * 4 + q];
    }

    // ---- online softmax: 8 lanes/row, chunk-strided (conflict-free) ----
    #pragma unroll
    for (int sh = 0; sh < 2; ++sh) {
      const int r  = sh * 64 + (t >> 3);
      const int cg = t & 7;
      // lane cg owns S cols {c*32 + cg*4 .. +3} for c = 0..3
      float4 v0 = *reinterpret_cast<const float4*>(swz(Sb, r, 512, 0 * 128 + cg * 16));
      float4 v1 = *reinterpret_cast<const float4*>(swz(Sb, r, 512, 1 * 128 + cg * 16));
      float4 v2 = *reinterpret_cast<const float4*>(swz(Sb, r, 512, 2 * 128 + cg * 16));
      float4 v3 = *reinterpret_cast<const float4*>(swz(Sb, r, 512, 3 * 128 + cg * 16));
      float vmax = fmaxf(fmaxf(fmaxf(v0.x, v0.y), fmaxf(v0.z, v0.w)),
                         fmaxf(fmaxf(v1.x, v1.y), fmaxf(v1.z, v1.w)));
      vmax = fmaxf(vmax, fmaxf(fmaxf(fmaxf(v2.x, v2.y), fmaxf(v2.z, v2.w)),
                               fmaxf(fmaxf(v3.x, v3.y), fmaxf(v3.z, v3.w))));
      vmax = fmaxf(vmax, __shfl_xor(vmax, 1, 8));
      vmax = fmaxf(vmax, __shfl_xor(vmax, 2, 8));
      vmax = fmaxf(vmax, __shfl_xor(vmax, 4, 8));
      const float m_old = row_m[r];
      const float m_new = fmaxf(m_old, vmax);

      float sum = 0.f;
      u16x4 pkc;
      float pv;
      // chunk 0
      pv = __expf(v0.x - m_new); sum += pv; pkc[0] = f2bf(pv);
      pv = __expf(v0.y - m_new); sum += pv; pkc[1] = f2bf(pv);
      pv = __expf(v0.z - m_new); sum += pv; pkc[2] = f2bf(pv);
      pv = __expf(v0.w - m_new); sum += pv; pkc[3] = f2bf(pv);
      *reinterpret_cast<u16x4*>(swz(Pb, r, 256, 0 * 64 + cg * 8)) = pkc;
      // chunk 1
      pv = __expf(v1.x - m_new); sum += pv; pkc[0] = f2bf(pv);
      pv = __expf(v1.y - m_new); sum += pv; pkc[1] = f2bf(pv);
      pv = __expf(v1.z - m_new); sum += pv; pkc[2] = f2bf(pv);
      pv = __expf(v1.w - m_new); sum += pv; pkc[3] = f2bf(pv);
      *reinterpret_cast<u16x4*>(swz(Pb, r, 256, 1 * 64 + cg * 8)) = pkc;
      // chunk 2
      pv = __expf(v2.x - m_new); sum += pv; pkc[0] = f2bf(pv);
      pv = __expf(v2.y - m_new); sum += pv; pkc[1] = f2bf(pv);
      pv = __expf(v2.z - m_new); sum += pv; pkc[2] = f2bf(pv);
      pv = __expf(v2.w - m_new); sum += pv; pkc[3] = f2bf(pv);
      *reinterpret_cast<u16x4*>(swz(Pb, r, 256, 2 * 64 + cg * 8)) = pkc;
      // chunk 3
      pv = __expf(v3.x - m_new); sum += pv; pkc[0] = f2bf(pv);
      pv = __expf(v3.y - m_new); sum += pv; pkc[1] = f2bf(pv);
      pv = __expf(v3.z - m_new); sum += pv; pkc[2] = f2bf(pv);
      pv = __expf(v3.w - m_new); sum += pv; pkc[3] = f2bf(pv);
      *reinterpret_cast<u16x4*>(swz(Pb, r, 256, 3 * 64 + cg * 8)) = pkc;

      sum += __shfl_xor(sum, 1, 8);
      sum += __shfl_xor(sum, 2, 8);
      sum += __shfl_xor(sum, 4, 8);
      if (cg == 0) {
        const float al = __expf(m_old - m_new);   // exp(-inf)=0 on iter 0
        row_alpha[r] = al;
        row_m[r]     = m_new;
        row_l[r]     = row_l[r] * al + sum;
      }
    }
    lds_barrier();

    // ---- rescale + PV for both halves (vb reused) ----
    PV_HALF(o_accA, 0);
    PV_HALF(o_accB, 64);
  }

  // ---- epilogue: normalized fp16 partials + (m,l) ----
  const size_t p = ((size_t)(n * 32 + qt)) * 2 + h;

#define EPI_HALF(OACC, RB)                                                   \
  do {                                                                       \
    _Pragma("unroll")                                                        \
    for (int ms = 0; ms < 4; ++ms) {                                         \
      float inv[4];                                                          \
      _Pragma("unroll")                                                      \
      for (int i = 0; i < 4; ++i)                                            \
        inv[i] = 1.0f / row_l[(RB) + ms * 16 + q * 4 + i];                   \
      _Pragma("unroll")                                                      \
      for (int nt = 0; nt < 2; ++nt)                                         \
        _Pragma("unroll")                                                    \
        for (int i = 0; i < 4; ++i) {                                        \
          const size_t oi =                                                  \
              (p * 128 + (RB) + ms * 16 + q * 4 + i) * 256 +                 \
              w * 32 + nt * 16 + mr;                                         \
          Opart[oi] = (_Float16)(OACC[ms][nt][i] * inv[i]);                  \
        }                                                                    \
    }                                                                        \
  } while (0)

  EPI_HALF(o_accA, 0);
  EPI_HALF(o_accB, 64);
  if (t < 128) {
    ML[p * 256 + t * 2]     = row_m[t];
    ML[p * 256 + t * 2 + 1] = row_l[t];
  }
}

// ---------------------------------------------------------------------------
// Pass 2b: merge the two key-halves + projection + residual (r8-verified).
// ---------------------------------------------------------------------------
__global__ __launch_bounds__(512) void pass2b(
    const _Float16* __restrict__ Opart,
    const float* __restrict__ ML,
    const unsigned short* __restrict__ pwb,
    const float* __restrict__ x,
    float* __restrict__ out)
{
  __shared__ __align__(16) unsigned char SMEM[34816];
  unsigned short (*Y_lds)[CH + 8] =
      reinterpret_cast<unsigned short(*)[CH + 8]>(SMEM);   // 64*264*2 = 33792
  float* w0 = reinterpret_cast<float*>(SMEM + 33792);      // 64 f32
  float* w1 = reinterpret_cast<float*>(SMEM + 34048);      // 64 f32

  const int t   = threadIdx.x;
  const int id  = blockIdx.x;
  const int n   = id >> 6;
  const int sub = id & 63;
  const int s0  = sub * 64;
  const int qt  = sub >> 1;
  const int rb  = (sub & 1) * 64;          // row range within the q-tile
  const size_t p0 = ((size_t)(n * 32 + qt)) * 2;

  if (t < 64) {
    const float ma = ML[p0 * 256 + (rb + t) * 2];
    const float la = ML[p0 * 256 + (rb + t) * 2 + 1];
    const float mb = ML[(p0 + 1) * 256 + (rb + t) * 2];
    const float lb = ML[(p0 + 1) * 256 + (rb + t) * 2 + 1];
    const float m  = fmaxf(ma, mb);
    const float e0 = __expf(ma - m) * la;
    const float e1 = __expf(mb - m) * lb;
    const float iL = 1.0f / (e0 + e1);
    w0[t] = e0 * iL;
    w1[t] = e1 * iL;
  }
  __syncthreads();

  // merge partials -> Y_lds (bf16)
  {
    const int r = t >> 3;
    #pragma unroll
    for (int seg = 0; seg < 4; ++seg) {
      const int c0 = (t & 7) * 8 + seg * 64;
      const size_t ai = (p0 * 128 + rb + r) * 256 + c0;
      const size_t bi = ((p0 + 1) * 128 + rb + r) * 256 + c0;
      h16x8 ha = *reinterpret_cast<const h16x8*>(Opart + ai);
      h16x8 hb = *reinterpret_cast<const h16x8*>(Opart + bi);
      u16x8 y;
      #pragma unroll
      for (int j = 0; j < 8; ++j)
        y[j] = f2bf((float)ha[j] * w0[r] + (float)hb[j] * w1[r]);
      *reinterpret_cast<u16x8*>(&Y_lds[r][c0]) = y;
    }
  }
  __syncthreads();

  // projection + residual: wave w -> output rows o = w*32 .. w*32+31
  const int w    = t >> 6;
  const int lane = t & 63;
  const int q    = lane >> 4;
  const int mr   = lane & 15;
  #pragma unroll
  for (int ot = 0; ot < 2; ++ot) {
    const int o0 = w * 32 + ot * 16;
    bfrag a[8];
    {
      const bfrag* ap = reinterpret_cast<const bfrag*>(pwb + (o0 + mr) * CH);
      #pragma unroll
      for (int k = 0; k < 8; ++k) a[k] = ap[k * 4 + q];
    }
    #pragma unroll
    for (int st = 0; st < 4; ++st) {
      f32x4 acc = {0.f, 0.f, 0.f, 0.f};
      const bfrag* bp = reinterpret_cast<const bfrag*>(&Y_lds[st * 16 + mr][0]);
      #pragma unroll
      for (int k = 0; k < 8; ++k)
        acc = __builtin_amdgcn_mfma_f32_16x16x32_bf16(a[k], bp[k * 4 + q], acc, 0, 0, 0);
      #pragma unroll
      for (int i = 0; i < 4; ++i) {
        const int o = o0 + q * 4 + i;
        const int s = s0 + st * 16 + mr;
        const size_t idx = ((size_t)n * CH + o) * SS + s;
        out[idx] = x[idx] + acc[i];
      }
    }
  }
}

// ---------------------------------------------------------------------------
// Fallback (ws too small for partials): round-5 fused full-key kernel,
// verbatim (measured 113.6 us; total 195.8 us). Fits in 16.6 MB workspace.
// ---------------------------------------------------------------------------
__global__ __launch_bounds__(512, 2) void pass2_full(
    const unsigned short* __restrict__ Qt,
    const unsigned short* __restrict__ Kt,
    const unsigned short* __restrict__ xb,
    const unsigned short* __restrict__ pwb,
    const float* __restrict__ x,
    float* __restrict__ out)
{
  __shared__ __align__(16) unsigned char SMEM[51968];
  float          (*S_lds)[132] = reinterpret_cast<float(*)[132]>(SMEM);
  unsigned short (*P_lds)[136] = reinterpret_cast<unsigned short(*)[136]>(SMEM + 33792);
  float* row_m     = reinterpret_cast<float*>(SMEM + 51200);
  float* row_l     = reinterpret_cast<float*>(SMEM + 51456);
  float* row_alpha = reinterpret_cast<float*>(SMEM + 51712);

  const int t    = threadIdx.x;
  const int id   = blockIdx.x;
  const int xcd  = id & 7;
  const int n    = xcd >> 1;
  const int s0   = ((id >> 3) * 2 + (xcd & 1)) * 64;
  const int w    = t >> 6;
  const int lane = t & 63;
  const int q    = lane >> 4;
  const int mr   = lane & 15;

  if (t < 64) { row_m[t] = -INFINITY; row_l[t] = 0.f; }

  bfrag qa[4][4];
  #pragma unroll
  for (int ms = 0; ms < 4; ++ms) {
    const bfrag* rp = reinterpret_cast<const bfrag*>(
        Qt + ((size_t)n * SS + s0 + ms * 16 + mr) * EE);
    #pragma unroll
    for (int k = 0; k < 4; ++k) qa[ms][k] = rp[k * 4 + q];
  }

  f32x4 o_acc[4][2];
  #pragma unroll
  for (int ms = 0; ms < 4; ++ms)
    #pragma unroll
    for (int nt = 0; nt < 2; ++nt) o_acc[ms][nt] = (f32x4){0.f, 0.f, 0.f, 0.f};

  bfrag kb[4];
  {
    const bfrag* rp = reinterpret_cast<const bfrag*>(
        Kt + ((size_t)n * SS + w * 16 + mr) * EE);
    #pragma unroll
    for (int k = 0; k < 4; ++k) kb[k] = rp[k * 4 + q];
  }

  for (int t0 = 0; t0 < SS; t0 += 128) {
    bfrag vb[4][2];
    #pragma unroll
    for (int nt = 0; nt < 2; ++nt) {
      const int c = w * 32 + nt * 16 + mr;
      const bfrag* vp = reinterpret_cast<const bfrag*>(
          xb + ((size_t)n * CH + c) * SS + t0);
      #pragma unroll
      for (int kk = 0; kk < 4; ++kk) vb[kk][nt] = vp[kk * 4 + q];
    }

    #pragma unroll
    for (int ms = 0; ms < 4; ++ms) {
      f32x4 acc = {0.f, 0.f, 0.f, 0.f};
      #pragma unroll
      for (int k = 0; k < 4; ++k)
        acc = __builtin_amdgcn_mfma_f32_16x16x32_bf16(qa[ms][k], kb[k], acc, 0, 0, 0);
      #pragma unroll
      for (int i = 0; i < 4; ++i)
        S_lds[ms * 16 + q * 4 + i][w * 16 + mr] = acc[i];
    }
    lds_barrier();

    {
      const int t1 = t0 + 128;
      if (t1 < SS) {
        const bfrag* rp = reinterpret_cast<const bfrag*>(
            Kt + ((size_t)n * SS + t1 + w * 16 + mr) * EE);
        #pragma unroll
        for (int k = 0; k < 4; ++k) kb[k] = rp[k * 4 + q];
      }
    }

    {
      const int r  = t >> 3;
      const int cg = t & 7;
      const float4* srow = reinterpret_cast<const float4*>(&S_lds[r][cg * 16]);
      float4 v0 = srow[0], v1 = srow[1], v2 = srow[2], v3 = srow[3];
      float vmax = fmaxf(fmaxf(fmaxf(v0.x, v0.y), fmaxf(v0.z, v0.w)),
                         fmaxf(fmaxf(v1.x, v1.y), fmaxf(v1.z, v1.w)));
      vmax = fmaxf(vmax, fmaxf(fmaxf(fmaxf(v2.x, v2.y), fmaxf(v2.z, v2.w)),
                               fmaxf(fmaxf(v3.x, v3.y), fmaxf(v3.z, v3.w))));
      vmax = fmaxf(vmax, __shfl_xor(vmax, 1, 8));
      vmax = fmaxf(vmax, __shfl_xor(vmax, 2, 8));
      vmax = fmaxf(vmax, __shfl_xor(vmax, 4, 8));
      const float m_old = row_m[r];
      const float m_new = fmaxf(m_old, vmax);

      float p[16];
      p[0]=__expf(v0.x-m_new); p[1]=__expf(v0.y-m_new); p[2]=__expf(v0.z-m_new); p[3]=__expf(v0.w-m_new);
      p[4]=__expf(v1.x-m_new); p[5]=__expf(v1.y-m_new); p[6]=__expf(v1.z-m_new); p[7]=__expf(v1.w-m_new);
      p[8]=__expf(v2.x-m_new); p[9]=__expf(v2.y-m_new); p[10]=__expf(v2.z-m_new); p[11]=__expf(v2.w-m_new);
      p[12]=__expf(v3.x-m_new); p[13]=__expf(v3.y-m_new); p[14]=__expf(v3.z-m_new); p[15]=__expf(v3.w-m_new);
      float sum = 0.f;
      u16x8 pk0, pk1;
      #pragma unroll
      for (int j = 0; j < 8; ++j) { sum += p[j];     pk0[j] = f2bf(p[j]); }
      #pragma unroll
      for (int j = 0; j < 8; ++j) { sum += p[8 + j]; pk1[j] = f2bf(p[8 + j]); }
      *reinterpret_cast<u16x8*>(&P_lds[r][cg * 16])     = pk0;
      *reinterpret_cast<u16x8*>(&P_lds[r][cg * 16 + 8]) = pk1;
      sum += __shfl_xor(sum, 1, 8);
      sum += __shfl_xor(sum, 2, 8);
      sum += __shfl_xor(sum, 4, 8);
      if (cg == 0) {
        const float al = __expf(m_old - m_new);
        row_alpha[r] = al;
        row_m[r]     = m_new;
        row_l[r]     = row_l[r] * al + sum;
      }
    }
    lds_barrier();

    #pragma unroll
    for (int ms = 0; ms < 4; ++ms) {
      float al[4];
      #pragma unroll
      for (int i = 0; i < 4; ++i) al[i] = row_alpha[ms * 16 + q * 4 + i];
      #pragma unroll
      for (int nt = 0; nt < 2; ++nt)
        #pragma unroll
        for (int i = 0; i < 4; ++i) o_acc[ms][nt][i] *= al[i];
    }

    #pragma unroll
    for (int kk = 0; kk < 4; ++kk) {
      bfrag pa[4];
      #pragma unroll
      for (int ms = 0; ms < 4; ++ms)
        pa[ms] = reinterpret_cast<const bfrag*>(&P_lds[ms * 16 + mr][0])[kk * 4 + q];
      #pragma unroll
      for (int nt = 0; nt < 2; ++nt)
        #pragma unroll
        for (int ms = 0; ms < 4; ++ms)
          o_acc[ms][nt] = __builtin_amdgcn_mfma_f32_16x16x32_bf16(
              pa[ms], vb[kk][nt], o_acc[ms][nt], 0, 0, 0);
    }
  }

  __syncthreads();
  unsigned short (*Y_lds)[CH + 8] =
      reinterpret_cast<unsigned short(*)[CH + 8]>(SMEM);

  #pragma unroll
  for (int ms = 0; ms < 4; ++ms) {
    float inv[4];
    #pragma unroll
    for (int i = 0; i < 4; ++i) inv[i] = 1.0f / row_l[ms * 16 + q * 4 + i];
    #pragma unroll
    for (int nt = 0; nt < 2; ++nt) {
      const int c = w * 32 + nt * 16 + mr;
      #pragma unroll
      for (int i = 0; i < 4; ++i)
        Y_lds[ms * 16 + q * 4 + i][c] = f2bf(o_acc[ms][nt][i] * inv[i]);
    }
  }
  __syncthreads();

  #pragma unroll
  for (int ot = 0; ot < 2; ++ot) {
    const int o0 = w * 32 + ot * 16;
    bfrag a[8];
    {
      const bfrag* ap = reinterpret_cast<const bfrag*>(pwb + (o0 + mr) * CH);
      #pragma unroll
      for (int k = 0; k < 8; ++k) a[k] = ap[k * 4 + q];
    }
    #pragma unroll
    for (int st = 0; st < 4; ++st) {
      f32x4 acc = {0.f, 0.f, 0.f, 0.f};
      const bfrag* bp = reinterpret_cast<const bfrag*>(&Y_lds[st * 16 + mr][0]);
      #pragma unroll
      for (int k = 0; k < 8; ++k)
        acc = __builtin_amdgcn_mfma_f32_16x16x32_bf16(a[k], bp[k * 4 + q], acc, 0, 0, 0);
      #pragma unroll
      for (int i = 0; i < 4; ++i) {
        const int o = o0 + q * 4 + i;
        const int s = s0 + st * 16 + mr;
        const size_t idx = ((size_t)n * CH + o) * SS + s;
        out[idx] = x[idx] + acc[i];
      }
    }
  }
}

// ---------------------------------------------------------------------------
extern "C" void kernel_launch(void* const* d_in, const int* in_sizes, int n_in,
                              void* d_out, int out_size, void* d_ws, size_t ws_size,
                              hipStream_t stream) {
  const float* x   = (const float*)d_in[0];
  const float* thw = (const float*)d_in[1];
  const float* phw = (const float*)d_in[2];
  const float* pw  = (const float*)d_in[3];
  float* out = (float*)d_out;

  unsigned short* xb   = (unsigned short*)d_ws;               // 8 MB
  unsigned short* Qt   = xb + (size_t)NB * CH * SS;           // 4 MB
  unsigned short* Kt   = Qt + (size_t)NB * SS * EE;           // 4 MB
  unsigned short* thwb = Kt + (size_t)NB * SS * EE;           // 64 KB
  unsigned short* phwb = thwb + EE * CH;                      // 64 KB
  unsigned short* pwb  = phwb + EE * CH;                      // 128 KB
  float*          ML   = (float*)(pwb + CH * CH);             // 256 KB
  _Float16*       Opart = (_Float16*)(ML + (size_t)256 * 128 * 2);

  // strict workspace gating (every Opart/ML byte covered)
  const size_t opart_off = (size_t)((char*)Opart - (char*)d_ws);
  const size_t opart_bytes = (size_t)256 * 128 * 256 * 2;     // 16.8 MB fp16
  const int fits = ws_size >= opart_off + opart_bytes;

  const int nw4 = EE * CH / 4;
  const int np4 = CH * CH / 4;
  const int totw4 = 2 * nw4 + np4;
  cvt_w<<<(totw4 + 255) / 256, 256, 0, stream>>>(thw, phw, pw, thwb, phwb, pwb);

  pass1_qk<<<dim3(SS / 64, NB), 512, 0, stream>>>(x, thwb, phwb, xb, Qt, Kt);

  if (fits) {
    pass2a<<<dim3(256), 512, 0, stream>>>(Qt, Kt, xb, Opart, ML);
    pass2b<<<dim3(256), 512, 0, stream>>>(Opart, ML, pwb, x, out);
  } else {
    pass2_full<<<dim3(NB * SS / 64), 512, 0, stream>>>(Qt, Kt, xb, pwb, x, out);
  }
}